// Round 18
// baseline (658.579 us; speedup 1.0000x reference)
//
#include <hip/hip_runtime.h>
#include <hip/hip_bf16.h>
#include <math.h>

typedef __bf16 bf16_t;
typedef __bf16 bf16x8 __attribute__((ext_vector_type(8)));
typedef float  f32x4 __attribute__((ext_vector_type(4)));
typedef float  f4    __attribute__((ext_vector_type(4)));
typedef float  f2    __attribute__((ext_vector_type(2)));
typedef unsigned short u16x4 __attribute__((ext_vector_type(4)));
typedef unsigned long long u64;

#define HS  512
#define BB  128
#define TT  40
#define VV  10000
#define VGGN 4096
#define SLOT ((size_t)65536)   // 128*512
#define NBLK 192               // 4 pipelines x (16 L0 + 32 L1)
#define NGRID 256              // + 64 dedicated logits workers (all join queue)
#define NTILE (TT * 79)        // logits tiles

// Per-slot counter lines, PER QUARTER-PIPELINE (u32 index; 64 u32=256B/line).
#define CL(qt, idx) ((((qt) * 164) + (idx)) * 64)
#define CRH0(qt,s) CL(qt, (s))
#define CHB0(qt,s) CL(qt, 41 + (s))
#define CRH1(qt,s) CL(qt, 82 + (s))
#define CHB1(qt,s) CL(qt, 123 + (s))
#define QLINE (656 * 64)       // logits work-queue counter
#define NSYNCW (657 * 64)

// ============================================================================
// Data-plane protocol (validated R12-R14): cross-block buffers are WRITE-ONCE
// slots; producers use agent-scope (L2-bypass) stores so L3 is current;
// consumers use PLAIN cached loads after the slot counter fires; entry
// __threadfence kills stale clean lines. u/h state in registers (R14).
// R17: independent batch-row pipelines. R18: 4 pipelines of 32 rows (quarter
// per-link bandwidth) + logits via global work-stealing queue (recurrence
// blocks join after their chains; all 256 blocks 1/CU -> co-resident).
// ============================================================================
__device__ __forceinline__ void cst64(void* p, u64 v) {
  __hip_atomic_store((u64*)p, v, __ATOMIC_RELAXED, __HIP_MEMORY_SCOPE_AGENT);
}

__device__ __forceinline__ void slot_inc(unsigned* sync, int line)
{
  __syncthreads();                 // drain agent stores (vmcnt(0) at barrier)
  asm volatile("" ::: "memory");
  if (threadIdx.x == 0)
    __hip_atomic_fetch_add(&sync[line], 1u, __ATOMIC_RELAXED,
                           __HIP_MEMORY_SCOPE_AGENT);
}

template<int SLP>
__device__ __forceinline__ void slot_wait(unsigned* sync, int line,
                                          unsigned target)
{
  if (threadIdx.x == 0) {
    while (__hip_atomic_load(&sync[line], __ATOMIC_RELAXED,
                             __HIP_MEMORY_SCOPE_AGENT) < target)
      __builtin_amdgcn_s_sleep(SLP);
  }
  asm volatile("" ::: "memory");
  __syncthreads();
}

template<int SLP>
__device__ __forceinline__ void slot_wait2(unsigned* sync, int lineA,
                                           unsigned tA, int lineB, unsigned tB)
{
  if (threadIdx.x == 0) {
    while (__hip_atomic_load(&sync[lineA], __ATOMIC_RELAXED,
                             __HIP_MEMORY_SCOPE_AGENT) < tA)
      __builtin_amdgcn_s_sleep(SLP);
    while (__hip_atomic_load(&sync[lineB], __ATOMIC_RELAXED,
                             __HIP_MEMORY_SCOPE_AGENT) < tB)
      __builtin_amdgcn_s_sleep(SLP);
  }
  asm volatile("" ::: "memory");
  __syncthreads();
}

__global__ void zero_sync(unsigned* p)
{
  for (int i = threadIdx.x; i < NSYNCW; i += 256) p[i] = 0u;
}

// ============================================================================
// Batched MFMA GEMM: C[M,N] = A[M,512] @ Bt[N,512]^T (+bias), fp32 out.
// (used for the xg0 pass)
// ============================================================================
__global__ __launch_bounds__(256) void gemm_bt(
    const bf16_t* __restrict__ A, const bf16_t* __restrict__ Bt,
    const float* __restrict__ bias, float* __restrict__ C,
    int Nvalid, int ldc, int permute_tb)
{
  const int bm = blockIdx.x * 128, bn = blockIdx.y * 128;
  const int tid = threadIdx.x;
  const int wave = tid >> 6, lane = tid & 63;
  const int wm = (wave >> 1) * 64, wn = (wave & 1) * 64;
  const int l15 = lane & 15, kg = lane >> 4;
  const bf16_t* Ap = A + (size_t)(bm + wm + l15) * 512 + kg * 8;
  const bf16_t* Bp = Bt + (size_t)(bn + wn + l15) * 512 + kg * 8;
  f32x4 acc[4][4];
#pragma unroll
  for (int i = 0; i < 4; ++i)
#pragma unroll
    for (int j = 0; j < 4; ++j)
#pragma unroll
      for (int e = 0; e < 4; ++e) acc[i][j][e] = 0.f;

  for (int kk = 0; kk < 512; kk += 32) {
    bf16x8 a[4], b[4];
#pragma unroll
    for (int i = 0; i < 4; ++i) a[i] = *(const bf16x8*)(Ap + (size_t)i * 16 * 512 + kk);
#pragma unroll
    for (int j = 0; j < 4; ++j) b[j] = *(const bf16x8*)(Bp + (size_t)j * 16 * 512 + kk);
#pragma unroll
    for (int i = 0; i < 4; ++i)
#pragma unroll
      for (int j = 0; j < 4; ++j)
        acc[i][j] = __builtin_amdgcn_mfma_f32_16x16x32_bf16(a[i], b[j], acc[i][j], 0, 0, 0);
  }

#pragma unroll
  for (int fm = 0; fm < 4; ++fm) {
#pragma unroll
    for (int fn = 0; fn < 4; ++fn) {
      int n = bn + wn + fn * 16 + l15;
      if (n >= Nvalid) continue;
      float bv = bias ? bias[n] : 0.f;
#pragma unroll
      for (int e = 0; e < 4; ++e) {
        int m = bm + wm + fm * 16 + kg * 4 + e;
        int orow = permute_tb ? ((m & 127) * TT + (m >> 7)) : m;
        C[(size_t)orow * ldc + n] = acc[fm][fn][e] + bv;
      }
    }
  }
}

// ============================================================================
// Quad-pipeline column-ownership persistent GRU + work-stealing logits.
//   blocks [0,192): qt = bid/48, b2 = bid%48, rows [qt*32, qt*32+32):
//     b2 in [0,16):  L0, owns H-cols [q*32,+32); waves = 2 rowgroups x 2 colfrags
//     b2 in [16,48): L1, owns H-cols [q*16,+16); waves = 2 rowgroups x 2 K-halves
//       (split-K: half0 = hb0 panel, half1 = hb1/rh1 panel; LDS reduce; h/u
//        state lives in the g=0 waves)
//   blocks [192,256): dedicated logits workers.
// All blocks finish in the logits work-queue (atomic tile pop; tiles t-major).
// ============================================================================
struct PArgs {
  const bf16_t *Btru0, *Bt1ru, *Btc0, *Btc1;
  const float  *xg0, *bu, *br, *bc, *hs0init;
  bf16_t *hb0_seq, *hb1_seq, *rh0s, *rh1s;
  const bf16_t *Wto;
  const float  *bo;
  float *out, *out_hfin;
  unsigned *sync;
};

__global__ __launch_bounds__(256) void gru_persist(PArgs P)
{
  const int bid = blockIdx.x, tid = threadIdx.x;
  const int wave = tid >> 6, lane = tid & 63;
  const int l15 = lane & 15, kg = lane >> 4;
  const int rg = wave >> 1, wsub = wave & 1;
  const int mwr = rg * 16;
  unsigned* sync = P.sync;

  __shared__ bf16_t Bs[49152];                  // [RU 64KB | C 32KB]
  __shared__ float paccs[2][32][33];            // L1 split-K partials (8.4KB)
  __shared__ unsigned short tb[32][36];         // publish transpose (2.3KB)
  __shared__ int qtile;
  bf16_t* BsRU = Bs;
  bf16_t* BsC  = Bs + 32768;

  // One-time per-block L2/L1 invalidate (stale clean-line protocol, R12).
  __threadfence();
  __syncthreads();

  if (bid < NBLK) {
    // =================== recurrence blocks =================================
    const int qt   = bid / 48;
    const int b2   = bid % 48;
    const int row0 = qt * 32;
    const bool L0  = (b2 < 16);
    const int q    = L0 ? b2 : b2 - 16;
    const int n0   = L0 ? q * 32 : q * 16;

    // ---- stage weights (swizzled) ----
    if (L0) {
      for (int c = tid; c < 4096; c += 256) {          // RU: 64 rows x 1KB
        int row = c >> 6, cb = (c & 63) * 16;
        const bf16_t* src = (row < 32) ? P.Btru0 + (size_t)(n0 + row) * 512
                                       : P.Btru0 + (size_t)(512 + n0 + row - 32) * 512;
        *(f4*)((char*)BsRU + row * 1024 + (cb ^ ((row & 7) << 4))) =
            *(const f4*)((const char*)src + cb);
      }
      for (int c = tid; c < 2048; c += 256) {          // C: 32 rows x 1KB
        int row = c >> 6, cb = (c & 63) * 16;
        const bf16_t* src = P.Btc0 + (size_t)(n0 + row) * 512;
        *(f4*)((char*)BsC + row * 1024 + (cb ^ ((row & 7) << 4))) =
            *(const f4*)((const char*)src + cb);
      }
    } else {
      for (int c = tid; c < 4096; c += 256) {          // RU: 32 rows x 2KB
        int row = c >> 7, cb = (c & 127) * 16;
        const bf16_t* src = (row < 16) ? P.Bt1ru + (size_t)(n0 + row) * 1024
                                       : P.Bt1ru + (size_t)(512 + n0 + row - 16) * 1024;
        *(f4*)((char*)BsRU + row * 2048 + (cb ^ ((row & 7) << 4))) =
            *(const f4*)((const char*)src + cb);
      }
      for (int c = tid; c < 2048; c += 256) {          // C: 16 rows x 2KB
        int row = c >> 7, cb = (c & 127) * 16;
        const bf16_t* src = P.Btc1 + (size_t)(n0 + row) * 1024;
        *(f4*)((char*)BsC + row * 2048 + (cb ^ ((row & 7) << 4))) =
            *(const f4*)((const char*)src + cb);
      }
    }
    __syncthreads();

    // ---- register state ----
    float hreg[4], ureg[4];
#pragma unroll
    for (int e = 0; e < 4; ++e) {
      int row = row0 + mwr + kg * 4 + e;
      int col = L0 ? (n0 + wsub * 16 + l15) : (n0 + l15);
      hreg[e] = P.hs0init[(size_t)row * 512 + col];
      ureg[e] = 0.f;
    }

    if (L0) {
      // =================== layer-0 chain ===================
      for (int s = 0; s < 40; ++s) {
        if (s >= 1) slot_wait<8>(sync, CHB0(qt, s), 16u);
        // RU0: 2 frags (u,r), K=512
        f32x4 au, ar;
#pragma unroll
        for (int e = 0; e < 4; ++e) { au[e] = 0.f; ar[e] = 0.f; }
        const bf16_t* A0 = P.hb0_seq + (size_t)s * SLOT + (size_t)row0 * 512;
        for (int kk = 0; kk < 512; kk += 32) {
          bf16x8 a = *(const bf16x8*)(A0 + (size_t)(mwr + l15) * 512 + kk + kg * 8);
          int rowu = wsub * 16 + l15;
          int rowr = 32 + wsub * 16 + l15;
          bf16x8 bu_ = *(const bf16x8*)((const char*)BsRU + rowu * 1024 +
                         ((2 * kk + 16 * kg) ^ ((rowu & 7) << 4)));
          bf16x8 br_ = *(const bf16x8*)((const char*)BsRU + rowr * 1024 +
                         ((2 * kk + 16 * kg) ^ ((rowr & 7) << 4)));
          au = __builtin_amdgcn_mfma_f32_16x16x32_bf16(a, bu_, au, 0, 0, 0);
          ar = __builtin_amdgcn_mfma_f32_16x16x32_bf16(a, br_, ar, 0, 0, 0);
        }
        const float* xg = P.xg0 + (size_t)s * 128 * 1536;
#pragma unroll
        for (int e = 0; e < 4; ++e) {
          int row = row0 + mwr + kg * 4 + e;
          int col = n0 + wsub * 16 + l15;
          float pu = au[e] + xg[(size_t)row * 1536 + col];
          float pr = ar[e] + xg[(size_t)row * 1536 + 512 + col];
          ureg[e] = 1.f / (1.f + expf(-pu));
          float rv = (1.f / (1.f + expf(-pr))) * hreg[e];
          tb[mwr + kg * 4 + e][wsub * 16 + l15] =
              __builtin_bit_cast(unsigned short, (bf16_t)rv);
        }
        __syncthreads();
        {   // store 32x32 bf16 -> rh0s[s] at (row0,n0): 256 u64
          int row = tid >> 3, cc = (tid & 7) * 4;
          u16x4 pk = { tb[row][cc], tb[row][cc+1], tb[row][cc+2], tb[row][cc+3] };
          cst64(P.rh0s + (size_t)s * SLOT + (size_t)(row0 + row) * 512 + n0 + cc,
                __builtin_bit_cast(u64, pk));
        }
        slot_inc(sync, CRH0(qt, s));
        slot_wait<8>(sync, CRH0(qt, s), 16u);
        // C0: 1 frag, K=512 over rh0s
        f32x4 ac;
#pragma unroll
        for (int e = 0; e < 4; ++e) ac[e] = 0.f;
        const bf16_t* Ar = P.rh0s + (size_t)s * SLOT + (size_t)row0 * 512;
        for (int kk = 0; kk < 512; kk += 32) {
          bf16x8 a = *(const bf16x8*)(Ar + (size_t)(mwr + l15) * 512 + kk + kg * 8);
          int rowc = wsub * 16 + l15;
          bf16x8 bc_ = *(const bf16x8*)((const char*)BsC + rowc * 1024 +
                         ((2 * kk + 16 * kg) ^ ((rowc & 7) << 4)));
          ac = __builtin_amdgcn_mfma_f32_16x16x32_bf16(a, bc_, ac, 0, 0, 0);
        }
#pragma unroll
        for (int e = 0; e < 4; ++e) {
          int row = row0 + mwr + kg * 4 + e;
          int col = n0 + wsub * 16 + l15;
          float c = tanhf(ac[e] + xg[(size_t)row * 1536 + 1024 + col]);
          hreg[e] = ureg[e] * hreg[e] + (1.f - ureg[e]) * c;
          tb[mwr + kg * 4 + e][wsub * 16 + l15] =
              __builtin_bit_cast(unsigned short, (bf16_t)hreg[e]);
        }
        __syncthreads();
        {
          int row = tid >> 3, cc = (tid & 7) * 4;
          u16x4 pk = { tb[row][cc], tb[row][cc+1], tb[row][cc+2], tb[row][cc+3] };
          cst64(P.hb0_seq + (size_t)(s + 1) * SLOT + (size_t)(row0 + row) * 512 + n0 + cc,
                __builtin_bit_cast(u64, pk));
        }
        slot_inc(sync, CHB0(qt, s + 1));
      }
      // h_final layer 0
#pragma unroll
      for (int e = 0; e < 4; ++e) {
        int row = row0 + mwr + kg * 4 + e;
        P.out_hfin[(size_t)row * 512 + n0 + wsub * 16 + l15] = hreg[e];
      }
    } else {
      // =================== layer-1 chain (split-K across wsub) ============
      for (int s = 1; s <= 40; ++s) {
        if (s >= 2) slot_wait2<8>(sync, CHB0(qt, s), 16u, CHB1(qt, s - 1), 32u);
        else        slot_wait<8>(sync, CHB0(qt, 1), 16u);
        // RU1 partials: wsub=0 -> hb0[s] x W[0:512); wsub=1 -> hb1[s-1] x W[512:1024)
        f32x4 au, ar;
#pragma unroll
        for (int e = 0; e < 4; ++e) { au[e] = 0.f; ar[e] = 0.f; }
        const bf16_t* Ap = (wsub ? P.hb1_seq + (size_t)(s - 1) * SLOT
                                 : P.hb0_seq + (size_t)s * SLOT) + (size_t)row0 * 512;
        for (int kk = 0; kk < 512; kk += 32) {
          bf16x8 a = *(const bf16x8*)(Ap + (size_t)(mwr + l15) * 512 + kk + kg * 8);
          int kglob = wsub * 512 + kk;
          int rowu = l15, rowr = 16 + l15;
          bf16x8 bu_ = *(const bf16x8*)((const char*)BsRU + rowu * 2048 +
                         ((2 * kglob + 16 * kg) ^ ((rowu & 7) << 4)));
          bf16x8 br_ = *(const bf16x8*)((const char*)BsRU + rowr * 2048 +
                         ((2 * kglob + 16 * kg) ^ ((rowr & 7) << 4)));
          au = __builtin_amdgcn_mfma_f32_16x16x32_bf16(a, bu_, au, 0, 0, 0);
          ar = __builtin_amdgcn_mfma_f32_16x16x32_bf16(a, br_, ar, 0, 0, 0);
        }
#pragma unroll
        for (int e = 0; e < 4; ++e) {
          paccs[wsub][mwr + kg * 4 + e][l15]      = au[e];
          paccs[wsub][mwr + kg * 4 + e][16 + l15] = ar[e];
        }
        __syncthreads();
        if (wsub == 0) {
          float bvu = P.bu[512 + n0 + l15];
          float bvr = P.br[512 + n0 + l15];
#pragma unroll
          for (int e = 0; e < 4; ++e) {
            int r = mwr + kg * 4 + e;
            float su = paccs[0][r][l15] + paccs[1][r][l15] + bvu;
            float sr = paccs[0][r][16 + l15] + paccs[1][r][16 + l15] + bvr;
            ureg[e] = 1.f / (1.f + expf(-su));
            float rv = (1.f / (1.f + expf(-sr))) * hreg[e];
            tb[r][l15] = __builtin_bit_cast(unsigned short, (bf16_t)rv);
          }
        }
        __syncthreads();
        if (tid < 128) {   // 32x16 bf16 -> rh1s[s]: 128 u64
          int row = tid >> 2, cc = (tid & 3) * 4;
          u16x4 pk = { tb[row][cc], tb[row][cc+1], tb[row][cc+2], tb[row][cc+3] };
          cst64(P.rh1s + (size_t)s * SLOT + (size_t)(row0 + row) * 512 + n0 + cc,
                __builtin_bit_cast(u64, pk));
        }
        slot_inc(sync, CRH1(qt, s));
        slot_wait<8>(sync, CRH1(qt, s), 32u);
        // C1 partials: wsub=0 -> hb0[s] x Wc[0:512); wsub=1 -> rh1[s] x Wc[512:1024)
        f32x4 ac;
#pragma unroll
        for (int e = 0; e < 4; ++e) ac[e] = 0.f;
        const bf16_t* Ac = (wsub ? P.rh1s + (size_t)s * SLOT
                                 : P.hb0_seq + (size_t)s * SLOT) + (size_t)row0 * 512;
        for (int kk = 0; kk < 512; kk += 32) {
          bf16x8 a = *(const bf16x8*)(Ac + (size_t)(mwr + l15) * 512 + kk + kg * 8);
          int kglob = wsub * 512 + kk;
          int rowc = l15;
          bf16x8 bc_ = *(const bf16x8*)((const char*)BsC + rowc * 2048 +
                         ((2 * kglob + 16 * kg) ^ ((rowc & 7) << 4)));
          ac = __builtin_amdgcn_mfma_f32_16x16x32_bf16(a, bc_, ac, 0, 0, 0);
        }
#pragma unroll
        for (int e = 0; e < 4; ++e)
          paccs[wsub][mwr + kg * 4 + e][l15] = ac[e];
        __syncthreads();
        if (wsub == 0) {
          float bvc = P.bc[512 + n0 + l15];
#pragma unroll
          for (int e = 0; e < 4; ++e) {
            int r = mwr + kg * 4 + e;
            float c = tanhf(paccs[0][r][l15] + paccs[1][r][l15] + bvc);
            hreg[e] = ureg[e] * hreg[e] + (1.f - ureg[e]) * c;
            tb[r][l15] = __builtin_bit_cast(unsigned short, (bf16_t)hreg[e]);
          }
        }
        __syncthreads();
        if (tid < 128) {
          int row = tid >> 2, cc = (tid & 3) * 4;
          u16x4 pk = { tb[row][cc], tb[row][cc+1], tb[row][cc+2], tb[row][cc+3] };
          cst64(P.hb1_seq + (size_t)s * SLOT + (size_t)(row0 + row) * 512 + n0 + cc,
                __builtin_bit_cast(u64, pk));
        }
        slot_inc(sync, CHB1(qt, s));
      }
      // h_final layer 1 (h lives in wsub==0 waves)
      if (wsub == 0) {
#pragma unroll
        for (int e = 0; e < 4; ++e) {
          int row = row0 + mwr + kg * 4 + e;
          P.out_hfin[65536 + (size_t)row * 512 + n0 + l15] = hreg[e];
        }
      }
      __syncthreads();
    }
  }

  // ===================== logits work-stealing queue ========================
  const int wm = (wave >> 1) * 64, wn = (wave & 1) * 64;
  for (;;) {
    if (tid == 0)
      qtile = (int)__hip_atomic_fetch_add(&sync[QLINE], 1u,
                                          __ATOMIC_RELAXED, __HIP_MEMORY_SCOPE_AGENT);
    __syncthreads();
    int tau = qtile;
    __syncthreads();
    if (tau >= NTILE) break;
    const int t = tau / 79, nb = tau % 79;
    if (tid == 0) {
#pragma unroll
      for (int qq = 0; qq < 4; ++qq) {
        while (__hip_atomic_load(&sync[CHB1(qq, t + 1)], __ATOMIC_RELAXED,
                                 __HIP_MEMORY_SCOPE_AGENT) < 32u)
          __builtin_amdgcn_s_sleep(16);
      }
    }
    asm volatile("" ::: "memory");
    __syncthreads();
    const bf16_t* A = P.hb1_seq + (size_t)(t + 1) * SLOT;
    const bf16_t* Bp = P.Wto + (size_t)(nb * 128 + wn + l15) * 512 + kg * 8;
    f32x4 acc[4][4];
#pragma unroll
    for (int i = 0; i < 4; ++i)
#pragma unroll
      for (int j = 0; j < 4; ++j)
#pragma unroll
        for (int e = 0; e < 4; ++e) acc[i][j][e] = 0.f;
    for (int kk = 0; kk < 512; kk += 32) {
      bf16x8 a[4], b[4];
#pragma unroll
      for (int i = 0; i < 4; ++i)
        a[i] = *(const bf16x8*)(A + (size_t)(wm + i * 16 + l15) * 512 + kk + kg * 8);
#pragma unroll
      for (int j = 0; j < 4; ++j)
        b[j] = *(const bf16x8*)(Bp + (size_t)j * 16 * 512 + kk);
#pragma unroll
      for (int i = 0; i < 4; ++i)
#pragma unroll
        for (int j = 0; j < 4; ++j)
          acc[i][j] = __builtin_amdgcn_mfma_f32_16x16x32_bf16(a[i], b[j], acc[i][j], 0, 0, 0);
    }
#pragma unroll
    for (int fm = 0; fm < 4; ++fm) {
#pragma unroll
      for (int fn = 0; fn < 4; ++fn) {
        int n = nb * 128 + wn + fn * 16 + l15;
        if (n >= VV) continue;
        float bv = P.bo[n];
#pragma unroll
        for (int e = 0; e < 4; ++e) {
          int b_row = wm + fm * 16 + kg * 4 + e;
          P.out[(size_t)(b_row * TT + t) * VV + n] = acc[fm][fn][e] + bv;
        }
      }
    }
    __syncthreads();
  }
}

// ============================================================================
// h0 = tanh(vgg @ W_in + b_in) via bf16 MFMA, split-K=8.
// ============================================================================
__global__ __launch_bounds__(256) void h0_gemm(
    const bf16_t* __restrict__ vggb, const bf16_t* __restrict__ Wint,
    float* __restrict__ part)
{
  const int bn = blockIdx.x * 128, z = blockIdx.y, k0 = z * 512;
  const int tid = threadIdx.x;
  const int wave = tid >> 6, lane = tid & 63;
  const int wm = (wave >> 1) * 64, wn = (wave & 1) * 64;
  const int l15 = lane & 15, kg = lane >> 4;
  const bf16_t* Ap = vggb + (size_t)(wm + l15) * 4096 + k0 + kg * 8;
  const bf16_t* Bp = Wint + (size_t)(bn + wn + l15) * 4096 + k0 + kg * 8;
  f32x4 acc[4][4];
#pragma unroll
  for (int i = 0; i < 4; ++i)
#pragma unroll
    for (int j = 0; j < 4; ++j)
#pragma unroll
      for (int e = 0; e < 4; ++e) acc[i][j][e] = 0.f;
  for (int kk = 0; kk < 512; kk += 32) {
    bf16x8 a[4], b[4];
#pragma unroll
    for (int i = 0; i < 4; ++i) a[i] = *(const bf16x8*)(Ap + (size_t)i * 16 * 4096 + kk);
#pragma unroll
    for (int j = 0; j < 4; ++j) b[j] = *(const bf16x8*)(Bp + (size_t)j * 16 * 4096 + kk);
#pragma unroll
    for (int i = 0; i < 4; ++i)
#pragma unroll
      for (int j = 0; j < 4; ++j)
        acc[i][j] = __builtin_amdgcn_mfma_f32_16x16x32_bf16(a[i], b[j], acc[i][j], 0, 0, 0);
  }
#pragma unroll
  for (int fm = 0; fm < 4; ++fm)
#pragma unroll
    for (int fn = 0; fn < 4; ++fn) {
      int n = bn + wn + fn * 16 + l15;
#pragma unroll
      for (int e = 0; e < 4; ++e) {
        int m = wm + fm * 16 + kg * 4 + e;
        part[(size_t)z * SLOT + m * 512 + n] = acc[fm][fn][e];
      }
    }
}

__global__ void h0_fin(const float* __restrict__ part, const float* __restrict__ bin,
                       float* __restrict__ hs0init,
                       bf16_t* __restrict__ hb00, bf16_t* __restrict__ hb10)
{
  int i = blockIdx.x * 256 + threadIdx.x;   // 65536
  int n = i & 511;
  float s = bin[n];
#pragma unroll
  for (int z = 0; z < 8; ++z) s += part[(size_t)z * SLOT + i];
  float v = tanhf(s);
  hs0init[i] = v;
  hb00[i] = (bf16_t)v; hb10[i] = (bf16_t)v;
}

__global__ void conv_bf16(const float* __restrict__ src, bf16_t* __restrict__ dst)
{
  int i = blockIdx.x * 256 + threadIdx.x;
  f4 v = ((const f4*)src)[i];
  dst[i * 4 + 0] = (bf16_t)v[0]; dst[i * 4 + 1] = (bf16_t)v[1];
  dst[i * 4 + 2] = (bf16_t)v[2]; dst[i * 4 + 3] = (bf16_t)v[3];
}

__global__ void gather_emb(const int* __restrict__ tok, const float* __restrict__ emb,
                           bf16_t* __restrict__ A)
{
  int m = blockIdx.x;
  int t = m >> 7, b = m & 127;
  int tk = tok[b * TT + t];
  const float* src = emb + (size_t)tk * 512;
  int i = threadIdx.x;
  f4 v = *(const f4*)(src + i * 4);
  bf16_t* dst = A + (size_t)m * 512 + i * 4;
  dst[0] = (bf16_t)v[0]; dst[1] = (bf16_t)v[1];
  dst[2] = (bf16_t)v[2]; dst[3] = (bf16_t)v[3];
}

struct TJob { const float* src; bf16_t* dst; int K; int dstld; };
struct TJobs10 { TJob j[10]; };
__global__ void transpose_gen(TJobs10 jobs)
{
  TJob jb = jobs.j[blockIdx.z];
  int k0 = blockIdx.x * 32;
  if (k0 >= jb.K) return;
  int n0 = blockIdx.y * 32;
  __shared__ float tile[32][33];
  int tx = threadIdx.x, ty = threadIdx.y;
#pragma unroll
  for (int r = 0; r < 4; ++r)
    tile[ty + 8 * r][tx] = jb.src[(size_t)(k0 + ty + 8 * r) * 512 + n0 + tx];
  __syncthreads();
#pragma unroll
  for (int r = 0; r < 4; ++r)
    jb.dst[(size_t)(n0 + ty + 8 * r) * jb.dstld + k0 + tx] = (bf16_t)tile[tx][ty + 8 * r];
}

__global__ void transpose_wout(const float* __restrict__ W, bf16_t* __restrict__ dst)
{
  __shared__ float tile[32][33];
  int k0 = blockIdx.x * 32, n0 = blockIdx.y * 32;
  int tx = threadIdx.x, ty = threadIdx.y;
#pragma unroll
  for (int r = 0; r < 4; ++r) {
    int n = n0 + tx;
    tile[ty + 8 * r][tx] = (n < VV) ? W[(size_t)(k0 + ty + 8 * r) * VV + n] : 0.f;
  }
  __syncthreads();
#pragma unroll
  for (int r = 0; r < 4; ++r)
    dst[(size_t)(n0 + ty + 8 * r) * 512 + k0 + tx] = (bf16_t)tile[tx][ty + 8 * r];
}

__global__ void build_xbias(const float* __restrict__ bu, const float* __restrict__ br,
                            const float* __restrict__ bc, float* __restrict__ xb)
{
  int i = blockIdx.x * 256 + threadIdx.x;
  if (i < 2 * 1536) {
    int j = i / 1536, qq = i % 1536;
    int g = qq >> 9, n = qq & 511;
    const float* src = (g == 0) ? bu : (g == 1) ? br : bc;
    xb[i] = src[j * 512 + n];
  }
}

// ============================================================================
extern "C" void kernel_launch(void* const* d_in, const int* in_sizes, int n_in,
                              void* d_out, int out_size, void* d_ws, size_t ws_size,
                              hipStream_t stream)
{
  const int*   tok = (const int*)  d_in[0];
  const float* vgg = (const float*)d_in[1];
  const float* emb = (const float*)d_in[2];
  const float* Win = (const float*)d_in[3];
  const float* bin = (const float*)d_in[4];
  const float* Wu  = (const float*)d_in[5];
  const float* bu  = (const float*)d_in[6];
  const float* Wr  = (const float*)d_in[7];
  const float* br  = (const float*)d_in[8];
  const float* Wc  = (const float*)d_in[9];
  const float* bc  = (const float*)d_in[10];
  const float* Wo  = (const float*)d_in[11];
  const float* bo  = (const float*)d_in[12];
  float* out = (float*)d_out;

  size_t off = 0;
  auto alloc = [&](size_t bytes) -> void* {
    void* p = (char*)d_ws + off;
    off += (bytes + 255) & ~(size_t)255;
    return p;
  };
  float*  hs0init = (float*) alloc(SLOT * 4);
  bf16_t* rh0s  = (bf16_t*)alloc(41 * SLOT * 2);
  bf16_t* rh1s  = (bf16_t*)alloc(41 * SLOT * 2);
  bf16_t* hb0_seq = (bf16_t*)alloc(41 * SLOT * 2);
  bf16_t* hb1_seq = (bf16_t*)alloc(41 * SLOT * 2);
  bf16_t* Aemb  = (bf16_t*)alloc((size_t)TT * BB * 512 * 2);
  float*  xg0   = (float*) alloc((size_t)TT * BB * 1536 * 4);
  bf16_t* Btx0  = (bf16_t*)alloc((size_t)1536 * 512 * 2);
  bf16_t* Btru0 = (bf16_t*)alloc((size_t)1024 * 512 * 2);
  bf16_t* Btc0  = (bf16_t*)alloc((size_t)512 * 512 * 2);
  bf16_t* Bt1ru = (bf16_t*)alloc((size_t)1024 * 1024 * 2);
  bf16_t* Btc1  = (bf16_t*)alloc((size_t)512 * 1024 * 2);
  bf16_t* Wto   = (bf16_t*)alloc((size_t)10112 * 512 * 2);
  bf16_t* Wint  = (bf16_t*)alloc((size_t)512 * 4096 * 2);
  bf16_t* vggb  = (bf16_t*)alloc((size_t)128 * 4096 * 2);
  float*  h0part= (float*) alloc(8 * SLOT * 4);
  float*  xbias = (float*) alloc(2 * 1536 * 4);
  unsigned* syncws = (unsigned*) alloc(NSYNCW * 4);
  if (off > ws_size) return;

  TJobs10 tj;
  tj.j[0] = { Wu,                Btx0,                512, 512 };
  tj.j[1] = { Wr,                Btx0 + 262144,       512, 512 };
  tj.j[2] = { Wc,                Btx0 + 524288,       512, 512 };
  tj.j[3] = { Wu + 262144,       Btru0,               512, 512 };
  tj.j[4] = { Wr + 262144,       Btru0 + 262144,      512, 512 };
  tj.j[5] = { Wc + 262144,       Btc0,                512, 512 };
  tj.j[6] = { Wu + 524288,       Bt1ru,               1024, 1024 };
  tj.j[7] = { Wr + 524288,       Bt1ru + 524288,      1024, 1024 };
  tj.j[8] = { Wc + 524288,       Btc1,                1024, 1024 };
  tj.j[9] = { Win,               Wint,                4096, 4096 };
  transpose_gen<<<dim3(128, 16, 10), dim3(32, 8), 0, stream>>>(tj);
  transpose_wout<<<dim3(16, 316), dim3(32, 8), 0, stream>>>(Wo, Wto);
  build_xbias<<<12, 256, 0, stream>>>(bu, br, bc, xbias);
  gather_emb<<<TT * BB, 128, 0, stream>>>(tok, emb, Aemb);
  conv_bf16<<<512, 256, 0, stream>>>(vgg, vggb);
  zero_sync<<<1, 256, 0, stream>>>(syncws);

  h0_gemm<<<dim3(4, 8), 256, 0, stream>>>(vggb, Wint, h0part);
  h0_fin<<<256, 256, 0, stream>>>(h0part, bin, hs0init, hb0_seq, hb1_seq);

  gemm_bt<<<dim3(40, 12), 256, 0, stream>>>(Aemb, Btx0, xbias, xg0, 1536, 1536, 0);

  PArgs pa;
  pa.Btru0 = Btru0; pa.Bt1ru = Bt1ru; pa.Btc0 = Btc0; pa.Btc1 = Btc1;
  pa.xg0 = xg0; pa.bu = bu; pa.br = br; pa.bc = bc; pa.hs0init = hs0init;
  pa.hb0_seq = hb0_seq; pa.hb1_seq = hb1_seq;
  pa.rh0s = rh0s; pa.rh1s = rh1s;
  pa.Wto = Wto; pa.bo = bo; pa.out = out;
  pa.out_hfin = out + (size_t)BB * TT * VV;
  pa.sync = syncws;
  gru_persist<<<NGRID, 256, 0, stream>>>(pa);
}

// Round 19
// 619.833 us; speedup vs baseline: 1.0625x; 1.0625x over previous
//
#include <hip/hip_runtime.h>
#include <hip/hip_bf16.h>
#include <math.h>

typedef __bf16 bf16_t;
typedef __bf16 bf16x8 __attribute__((ext_vector_type(8)));
typedef float  f32x4 __attribute__((ext_vector_type(4)));
typedef float  f4    __attribute__((ext_vector_type(4)));
typedef float  f2    __attribute__((ext_vector_type(2)));
typedef unsigned short u16x4 __attribute__((ext_vector_type(4)));
typedef unsigned long long u64;

#define HS  512
#define BB  128
#define TT  40
#define VV  10000
#define VGGN 4096
#define SLOT ((size_t)65536)   // 128*512
#define NBLK 96                // 2 pipelines x (16 L0 + 32 L1)
#define NGRID 256              // + 160 logits workers

// Per-slot counter lines, PER HALF-PIPELINE (u32 index; 64 u32 = 256B/line).
#define CL(h, idx) ((((h) * 164) + (idx)) * 64)
#define CRH0(h,s) CL(h, (s))
#define CHB0(h,s) CL(h, 41 + (s))
#define CRH1(h,s) CL(h, 82 + (s))
#define CHB1(h,s) CL(h, 123 + (s))
#define NSYNCW (328 * 64)

// ============================================================================
// Data-plane protocol (validated R12-R17): cross-block buffers are WRITE-ONCE
// slots; producers use agent-scope (L2-bypass) stores so L3 is current;
// consumers use PLAIN cached loads after the slot counter fires; entry
// __threadfence kills stale clean lines. u/h in registers (column-ownership).
// Two free-running 64-row pipelines (R17). R19: dependency-free xg/bias loads
// hoisted BEFORE slot_wait so their latency hides under the poll.
// ============================================================================
__device__ __forceinline__ void cst64(void* p, u64 v) {
  __hip_atomic_store((u64*)p, v, __ATOMIC_RELAXED, __HIP_MEMORY_SCOPE_AGENT);
}

__device__ __forceinline__ void slot_inc(unsigned* sync, int line)
{
  __syncthreads();                 // drain agent stores (vmcnt(0) at barrier)
  asm volatile("" ::: "memory");
  if (threadIdx.x == 0)
    __hip_atomic_fetch_add(&sync[line], 1u, __ATOMIC_RELAXED,
                           __HIP_MEMORY_SCOPE_AGENT);
}

template<int SLP>
__device__ __forceinline__ void slot_wait(unsigned* sync, int line,
                                          unsigned target)
{
  if (threadIdx.x == 0) {
    while (__hip_atomic_load(&sync[line], __ATOMIC_RELAXED,
                             __HIP_MEMORY_SCOPE_AGENT) < target)
      __builtin_amdgcn_s_sleep(SLP);
  }
  asm volatile("" ::: "memory");
  __syncthreads();
}

template<int SLP>
__device__ __forceinline__ void slot_wait2(unsigned* sync, int lineA,
                                           unsigned tA, int lineB, unsigned tB)
{
  if (threadIdx.x == 0) {
    while (__hip_atomic_load(&sync[lineA], __ATOMIC_RELAXED,
                             __HIP_MEMORY_SCOPE_AGENT) < tA)
      __builtin_amdgcn_s_sleep(SLP);
    while (__hip_atomic_load(&sync[lineB], __ATOMIC_RELAXED,
                             __HIP_MEMORY_SCOPE_AGENT) < tB)
      __builtin_amdgcn_s_sleep(SLP);
  }
  asm volatile("" ::: "memory");
  __syncthreads();
}

__global__ void zero_sync(unsigned* p)
{
  for (int i = threadIdx.x; i < NSYNCW; i += 256) p[i] = 0u;
}

// ============================================================================
// Batched MFMA GEMM: C[M,N] = A[M,512] @ Bt[N,512]^T (+bias), fp32 out.
// (used for the xg0 pass)
// ============================================================================
__global__ __launch_bounds__(256) void gemm_bt(
    const bf16_t* __restrict__ A, const bf16_t* __restrict__ Bt,
    const float* __restrict__ bias, float* __restrict__ C,
    int Nvalid, int ldc, int permute_tb)
{
  const int bm = blockIdx.x * 128, bn = blockIdx.y * 128;
  const int tid = threadIdx.x;
  const int wave = tid >> 6, lane = tid & 63;
  const int wm = (wave >> 1) * 64, wn = (wave & 1) * 64;
  const int l15 = lane & 15, kg = lane >> 4;
  const bf16_t* Ap = A + (size_t)(bm + wm + l15) * 512 + kg * 8;
  const bf16_t* Bp = Bt + (size_t)(bn + wn + l15) * 512 + kg * 8;
  f32x4 acc[4][4];
#pragma unroll
  for (int i = 0; i < 4; ++i)
#pragma unroll
    for (int j = 0; j < 4; ++j)
#pragma unroll
      for (int e = 0; e < 4; ++e) acc[i][j][e] = 0.f;

  for (int kk = 0; kk < 512; kk += 32) {
    bf16x8 a[4], b[4];
#pragma unroll
    for (int i = 0; i < 4; ++i) a[i] = *(const bf16x8*)(Ap + (size_t)i * 16 * 512 + kk);
#pragma unroll
    for (int j = 0; j < 4; ++j) b[j] = *(const bf16x8*)(Bp + (size_t)j * 16 * 512 + kk);
#pragma unroll
    for (int i = 0; i < 4; ++i)
#pragma unroll
      for (int j = 0; j < 4; ++j)
        acc[i][j] = __builtin_amdgcn_mfma_f32_16x16x32_bf16(a[i], b[j], acc[i][j], 0, 0, 0);
  }

#pragma unroll
  for (int fm = 0; fm < 4; ++fm) {
#pragma unroll
    for (int fn = 0; fn < 4; ++fn) {
      int n = bn + wn + fn * 16 + l15;
      if (n >= Nvalid) continue;
      float bv = bias ? bias[n] : 0.f;
#pragma unroll
      for (int e = 0; e < 4; ++e) {
        int m = bm + wm + fm * 16 + kg * 4 + e;
        int orow = permute_tb ? ((m & 127) * TT + (m >> 7)) : m;
        C[(size_t)orow * ldc + n] = acc[fm][fn][e] + bv;
      }
    }
  }
}

// ============================================================================
// Dual-pipeline column-ownership persistent GRU + fused logits (R17 structure).
// ============================================================================
struct PArgs {
  const bf16_t *Btru0, *Bt1ru, *Btc0, *Btc1;
  const float  *xg0, *bu, *br, *bc, *hs0init;
  bf16_t *hb0_seq, *hb1_seq, *rh0s, *rh1s;
  const bf16_t *Wto;
  const float  *bo;
  float *out, *out_hfin;
  unsigned *sync;
};

template<int K, int NF>
__device__ __forceinline__ void tile_gemm64(
    const bf16_t* __restrict__ A0, const bf16_t* __restrict__ A1,
    const bf16_t* Bs, int wave, int lane, f32x4 (&acc)[NF])
{
  const int l15 = lane & 15, kg = lane >> 4;
  const int mw = wave * 16;
#pragma unroll
  for (int f = 0; f < NF; ++f)
#pragma unroll
    for (int e = 0; e < 4; ++e) acc[f][e] = 0.f;

#pragma unroll
  for (int kk = 0; kk < K; kk += 32) {
    const bf16_t* Asrc = (kk < 512) ? A0 : A1;
    const int kc = (kk < 512 ? kk : kk - 512) + kg * 8;
    bf16x8 a = *(const bf16x8*)(Asrc + (size_t)(mw + l15) * 512 + kc);
    bf16x8 b[NF];
#pragma unroll
    for (int f = 0; f < NF; ++f) {
      int row = f * 16 + l15;
      int byteoff = row * (2 * K) + ((2 * kk + 16 * kg) ^ ((row & 7) << 4));
      b[f] = *(const bf16x8*)((const char*)Bs + byteoff);
    }
#pragma unroll
    for (int f = 0; f < NF; ++f)
      acc[f] = __builtin_amdgcn_mfma_f32_16x16x32_bf16(a, b[f], acc[f], 0, 0, 0);
  }
}

template<int C>
__device__ __forceinline__ void publish64(
    bf16_t* dst, int row0, int n0, float (&v)[2][4],
    unsigned short (*tb)[36], int wave, int lane, int tid)
{
  const int l15 = lane & 15, kg = lane >> 4;
  const int mw = wave * 16;
  constexpr int NFp = C / 16;
#pragma unroll
  for (int f = 0; f < NFp; ++f)
#pragma unroll
    for (int e = 0; e < 4; ++e)
      tb[mw + kg * 4 + e][f * 16 + l15] =
          __builtin_bit_cast(unsigned short, (bf16_t)v[f][e]);
  __syncthreads();
  constexpr int NU = 64 * C / 4;        // u64 stores
  constexpr int IT = (NU + 255) / 256;
#pragma unroll
  for (int it = 0; it < IT; ++it) {
    int lin = it * 256 + tid;
    if (lin < NU) {
      int row = lin / (C / 4);
      int cc  = (lin % (C / 4)) * 4;
      u16x4 pk = { tb[row][cc], tb[row][cc + 1], tb[row][cc + 2], tb[row][cc + 3] };
      cst64(dst + (size_t)(row0 + row) * 512 + n0 + cc, __builtin_bit_cast(u64, pk));
    }
  }
}

__global__ __launch_bounds__(256) void gru_persist(PArgs P)
{
  const int bid = blockIdx.x, tid = threadIdx.x;
  const int wave = tid >> 6, lane = tid & 63;
  const int l15 = lane & 15, kg = lane >> 4;
  unsigned* sync = P.sync;

  __threadfence();
  __syncthreads();

  // ===================== logits worker blocks =====================
  if (bid >= NBLK) {
    const int w = bid - NBLK;                 // 0..159
    const int wm = (wave >> 1) * 64, wn = (wave & 1) * 64;
    for (int tau = w; tau < TT * 79; tau += (NGRID - NBLK)) {
      const int t = tau / 79, nb = tau % 79;
      slot_wait2<64>(sync, CHB1(0, t + 1), 32u, CHB1(1, t + 1), 32u);
      const bf16_t* A = P.hb1_seq + (size_t)(t + 1) * SLOT;
      const bf16_t* Bp = P.Wto + (size_t)(nb * 128 + wn + l15) * 512 + kg * 8;
      f32x4 acc[4][4];
#pragma unroll
      for (int i = 0; i < 4; ++i)
#pragma unroll
        for (int j = 0; j < 4; ++j)
#pragma unroll
          for (int e = 0; e < 4; ++e) acc[i][j][e] = 0.f;
      for (int kk = 0; kk < 512; kk += 32) {
        bf16x8 a[4], b[4];
#pragma unroll
        for (int i = 0; i < 4; ++i)
          a[i] = *(const bf16x8*)(A + (size_t)(wm + i * 16 + l15) * 512 + kk + kg * 8);
#pragma unroll
        for (int j = 0; j < 4; ++j)
          b[j] = *(const bf16x8*)(Bp + (size_t)j * 16 * 512 + kk);
#pragma unroll
        for (int i = 0; i < 4; ++i)
#pragma unroll
          for (int j = 0; j < 4; ++j)
            acc[i][j] = __builtin_amdgcn_mfma_f32_16x16x32_bf16(a[i], b[j], acc[i][j], 0, 0, 0);
      }
#pragma unroll
      for (int fm = 0; fm < 4; ++fm) {
#pragma unroll
        for (int fn = 0; fn < 4; ++fn) {
          int n = nb * 128 + wn + fn * 16 + l15;
          if (n >= VV) continue;
          float bv = P.bo[n];
#pragma unroll
          for (int e = 0; e < 4; ++e) {
            int b_row = wm + fm * 16 + kg * 4 + e;
            P.out[(size_t)(b_row * TT + t) * VV + n] = acc[fm][fn][e] + bv;
          }
        }
      }
      __syncthreads();
    }
    return;
  }

  // ===================== recurrence blocks ================================
  const int half = bid / 48;
  const int b2   = bid % 48;
  const int row0 = half * 64;
  const bool L0 = (b2 < 16);
  const int q  = L0 ? b2 : b2 - 16;
  const int n0 = L0 ? q * 32 : q * 16;
  const int mw = wave * 16;

  __shared__ bf16_t Bs[49152];                  // [RU 64KB | C 32KB]
  __shared__ unsigned short tb[64][36];
  bf16_t* BsRU = Bs;
  bf16_t* BsC  = Bs + 32768;

  if (L0) {
    for (int c = tid; c < 4096; c += 256) {
      int row = c >> 6, cb = (c & 63) * 16;
      const bf16_t* src = (row < 32) ? P.Btru0 + (size_t)(n0 + row) * 512
                                     : P.Btru0 + (size_t)(512 + n0 + row - 32) * 512;
      *(f4*)((char*)BsRU + row * 1024 + (cb ^ ((row & 7) << 4))) =
          *(const f4*)((const char*)src + cb);
    }
    for (int c = tid; c < 2048; c += 256) {
      int row = c >> 6, cb = (c & 63) * 16;
      const bf16_t* src = P.Btc0 + (size_t)(n0 + row) * 512;
      *(f4*)((char*)BsC + row * 1024 + (cb ^ ((row & 7) << 4))) =
          *(const f4*)((const char*)src + cb);
    }
  } else {
    for (int c = tid; c < 4096; c += 256) {
      int row = c >> 7, cb = (c & 127) * 16;
      const bf16_t* src = (row < 16) ? P.Bt1ru + (size_t)(n0 + row) * 1024
                                     : P.Bt1ru + (size_t)(512 + n0 + row - 16) * 1024;
      *(f4*)((char*)BsRU + row * 2048 + (cb ^ ((row & 7) << 4))) =
          *(const f4*)((const char*)src + cb);
    }
    for (int c = tid; c < 2048; c += 256) {
      int row = c >> 7, cb = (c & 127) * 16;
      const bf16_t* src = P.Btc1 + (size_t)(n0 + row) * 1024;
      *(f4*)((char*)BsC + row * 2048 + (cb ^ ((row & 7) << 4))) =
          *(const f4*)((const char*)src + cb);
    }
  }
  __syncthreads();

  const int NFh = L0 ? 2 : 1;
  float hreg[2][4], ureg[2][4], rhv[2][4];
#pragma unroll
  for (int f = 0; f < 2; ++f)
#pragma unroll
    for (int e = 0; e < 4; ++e) {
      int row = row0 + mw + kg * 4 + e;
      hreg[f][e] = (f < NFh)
          ? P.hs0init[(size_t)row * 512 + n0 + f * 16 + l15] : 0.f;
      ureg[f][e] = 0.f; rhv[f][e] = 0.f;
    }

  if (L0) {
    for (int s = 0; s < 40; ++s) {
      const float* xg = P.xg0 + (size_t)s * 128 * 1536;
      float xvu[2][4], xvr[2][4];
#pragma unroll
      for (int f = 0; f < 2; ++f)
#pragma unroll
        for (int e = 0; e < 4; ++e) {
          int row = row0 + mw + kg * 4 + e;
          int col = n0 + f * 16 + l15;
          xvu[f][e] = xg[(size_t)row * 1536 + col];
          xvr[f][e] = xg[(size_t)row * 1536 + 512 + col];
        }
      if (s >= 1) slot_wait<8>(sync, CHB0(half, s), 16u);
      f32x4 acc4[4];
      const bf16_t* A0 = P.hb0_seq + (size_t)s * SLOT + (size_t)row0 * 512;
      tile_gemm64<512, 4>(A0, A0, BsRU, wave, lane, acc4);
#pragma unroll
      for (int f = 0; f < 2; ++f)
#pragma unroll
        for (int e = 0; e < 4; ++e) {
          float pu = acc4[f][e]     + xvu[f][e];
          float pr = acc4[f + 2][e] + xvr[f][e];
          ureg[f][e] = 1.f / (1.f + expf(-pu));
          rhv[f][e]  = (1.f / (1.f + expf(-pr))) * hreg[f][e];
        }
      publish64<32>(P.rh0s + (size_t)s * SLOT, row0, n0, rhv, tb, wave, lane, tid);
      slot_inc(sync, CRH0(half, s));
      float xvc[2][4];
#pragma unroll
      for (int f = 0; f < 2; ++f)
#pragma unroll
        for (int e = 0; e < 4; ++e) {
          int row = row0 + mw + kg * 4 + e;
          int col = n0 + f * 16 + l15;
          xvc[f][e] = xg[(size_t)row * 1536 + 1024 + col];
        }
      slot_wait<8>(sync, CRH0(half, s), 16u);

      f32x4 acc2[2];
      const bf16_t* Arh = P.rh0s + (size_t)s * SLOT + (size_t)row0 * 512;
      tile_gemm64<512, 2>(Arh, Arh, BsC, wave, lane, acc2);
#pragma unroll
      for (int f = 0; f < 2; ++f)
#pragma unroll
        for (int e = 0; e < 4; ++e) {
          float c = tanhf(acc2[f][e] + xvc[f][e]);
          float u = ureg[f][e];
          hreg[f][e] = u * hreg[f][e] + (1.f - u) * c;
          rhv[f][e] = hreg[f][e];
        }
      publish64<32>(P.hb0_seq + (size_t)(s + 1) * SLOT, row0, n0, rhv, tb, wave, lane, tid);
      slot_inc(sync, CHB0(half, s + 1));
    }
  } else {
    const float bvu = P.bu[512 + n0 + l15];
    const float bvr = P.br[512 + n0 + l15];
    const float bvc = P.bc[512 + n0 + l15];
    for (int s = 1; s <= 40; ++s) {
      if (s >= 2) slot_wait2<8>(sync, CHB0(half, s), 16u, CHB1(half, s - 1), 32u);
      else        slot_wait<8>(sync, CHB0(half, 1), 16u);
      f32x4 acc2[2];
      tile_gemm64<1024, 2>(P.hb0_seq + (size_t)s * SLOT + (size_t)row0 * 512,
                           P.hb1_seq + (size_t)(s - 1) * SLOT + (size_t)row0 * 512,
                           BsRU, wave, lane, acc2);
#pragma unroll
      for (int e = 0; e < 4; ++e) {
        float pu = acc2[0][e] + bvu;
        float pr = acc2[1][e] + bvr;
        ureg[0][e] = 1.f / (1.f + expf(-pu));
        rhv[0][e]  = (1.f / (1.f + expf(-pr))) * hreg[0][e];
      }
      publish64<16>(P.rh1s + (size_t)s * SLOT, row0, n0, rhv, tb, wave, lane, tid);
      slot_inc(sync, CRH1(half, s));
      slot_wait<8>(sync, CRH1(half, s), 32u);

      f32x4 acc1[1];
      tile_gemm64<1024, 1>(P.hb0_seq + (size_t)s * SLOT + (size_t)row0 * 512,
                           P.rh1s + (size_t)s * SLOT + (size_t)row0 * 512,
                           BsC, wave, lane, acc1);
#pragma unroll
      for (int e = 0; e < 4; ++e) {
        float c = tanhf(acc1[0][e] + bvc);
        float u = ureg[0][e];
        hreg[0][e] = u * hreg[0][e] + (1.f - u) * c;
        rhv[0][e] = hreg[0][e];
      }
      publish64<16>(P.hb1_seq + (size_t)s * SLOT, row0, n0, rhv, tb, wave, lane, tid);
      slot_inc(sync, CHB1(half, s));
    }
  }

  float* dst = P.out_hfin + (L0 ? 0 : 65536);
#pragma unroll
  for (int f = 0; f < 2; ++f)
    if (f < NFh)
#pragma unroll
      for (int e = 0; e < 4; ++e) {
        int row = row0 + mw + kg * 4 + e;
        dst[(size_t)row * 512 + n0 + f * 16 + l15] = hreg[f][e];
      }
}

// ============================================================================
// h0 = tanh(vgg @ W_in + b_in) via bf16 MFMA, split-K=8.
// ============================================================================
__global__ __launch_bounds__(256) void h0_gemm(
    const bf16_t* __restrict__ vggb, const bf16_t* __restrict__ Wint,
    float* __restrict__ part)
{
  const int bn = blockIdx.x * 128, z = blockIdx.y, k0 = z * 512;
  const int tid = threadIdx.x;
  const int wave = tid >> 6, lane = tid & 63;
  const int wm = (wave >> 1) * 64, wn = (wave & 1) * 64;
  const int l15 = lane & 15, kg = lane >> 4;
  const bf16_t* Ap = vggb + (size_t)(wm + l15) * 4096 + k0 + kg * 8;
  const bf16_t* Bp = Wint + (size_t)(bn + wn + l15) * 4096 + k0 + kg * 8;
  f32x4 acc[4][4];
#pragma unroll
  for (int i = 0; i < 4; ++i)
#pragma unroll
    for (int j = 0; j < 4; ++j)
#pragma unroll
      for (int e = 0; e < 4; ++e) acc[i][j][e] = 0.f;
  for (int kk = 0; kk < 512; kk += 32) {
    bf16x8 a[4], b[4];
#pragma unroll
    for (int i = 0; i < 4; ++i) a[i] = *(const bf16x8*)(Ap + (size_t)i * 16 * 4096 + kk);
#pragma unroll
    for (int j = 0; j < 4; ++j) b[j] = *(const bf16x8*)(Bp + (size_t)j * 16 * 4096 + kk);
#pragma unroll
    for (int i = 0; i < 4; ++i)
#pragma unroll
      for (int j = 0; j < 4; ++j)
        acc[i][j] = __builtin_amdgcn_mfma_f32_16x16x32_bf16(a[i], b[j], acc[i][j], 0, 0, 0);
  }
#pragma unroll
  for (int fm = 0; fm < 4; ++fm)
#pragma unroll
    for (int fn = 0; fn < 4; ++fn) {
      int n = bn + wn + fn * 16 + l15;
#pragma unroll
      for (int e = 0; e < 4; ++e) {
        int m = wm + fm * 16 + kg * 4 + e;
        part[(size_t)z * SLOT + m * 512 + n] = acc[fm][fn][e];
      }
    }
}

__global__ void h0_fin(const float* __restrict__ part, const float* __restrict__ bin,
                       float* __restrict__ hs0init,
                       bf16_t* __restrict__ hb00, bf16_t* __restrict__ hb10)
{
  int i = blockIdx.x * 256 + threadIdx.x;   // 65536
  int n = i & 511;
  float s = bin[n];
#pragma unroll
  for (int z = 0; z < 8; ++z) s += part[(size_t)z * SLOT + i];
  float v = tanhf(s);
  hs0init[i] = v;
  hb00[i] = (bf16_t)v; hb10[i] = (bf16_t)v;
}

__global__ void conv_bf16(const float* __restrict__ src, bf16_t* __restrict__ dst)
{
  int i = blockIdx.x * 256 + threadIdx.x;
  f4 v = ((const f4*)src)[i];
  dst[i * 4 + 0] = (bf16_t)v[0]; dst[i * 4 + 1] = (bf16_t)v[1];
  dst[i * 4 + 2] = (bf16_t)v[2]; dst[i * 4 + 3] = (bf16_t)v[3];
}

__global__ void gather_emb(const int* __restrict__ tok, const float* __restrict__ emb,
                           bf16_t* __restrict__ A)
{
  int m = blockIdx.x;
  int t = m >> 7, b = m & 127;
  int tk = tok[b * TT + t];
  const float* src = emb + (size_t)tk * 512;
  int i = threadIdx.x;
  f4 v = *(const f4*)(src + i * 4);
  bf16_t* dst = A + (size_t)m * 512 + i * 4;
  dst[0] = (bf16_t)v[0]; dst[1] = (bf16_t)v[1];
  dst[2] = (bf16_t)v[2]; dst[3] = (bf16_t)v[3];
}

struct TJob { const float* src; bf16_t* dst; int K; int dstld; };
struct TJobs10 { TJob j[10]; };
__global__ void transpose_gen(TJobs10 jobs)
{
  TJob jb = jobs.j[blockIdx.z];
  int k0 = blockIdx.x * 32;
  if (k0 >= jb.K) return;
  int n0 = blockIdx.y * 32;
  __shared__ float tile[32][33];
  int tx = threadIdx.x, ty = threadIdx.y;
#pragma unroll
  for (int r = 0; r < 4; ++r)
    tile[ty + 8 * r][tx] = jb.src[(size_t)(k0 + ty + 8 * r) * 512 + n0 + tx];
  __syncthreads();
#pragma unroll
  for (int r = 0; r < 4; ++r)
    jb.dst[(size_t)(n0 + ty + 8 * r) * jb.dstld + k0 + tx] = (bf16_t)tile[tx][ty + 8 * r];
}

__global__ void transpose_wout(const float* __restrict__ W, bf16_t* __restrict__ dst)
{
  __shared__ float tile[32][33];
  int k0 = blockIdx.x * 32, n0 = blockIdx.y * 32;
  int tx = threadIdx.x, ty = threadIdx.y;
#pragma unroll
  for (int r = 0; r < 4; ++r) {
    int n = n0 + tx;
    tile[ty + 8 * r][tx] = (n < VV) ? W[(size_t)(k0 + ty + 8 * r) * VV + n] : 0.f;
  }
  __syncthreads();
#pragma unroll
  for (int r = 0; r < 4; ++r)
    dst[(size_t)(n0 + ty + 8 * r) * 512 + k0 + tx] = (bf16_t)tile[tx][ty + 8 * r];
}

__global__ void build_xbias(const float* __restrict__ bu, const float* __restrict__ br,
                            const float* __restrict__ bc, float* __restrict__ xb)
{
  int i = blockIdx.x * 256 + threadIdx.x;
  if (i < 2 * 1536) {
    int j = i / 1536, qq = i % 1536;
    int g = qq >> 9, n = qq & 511;
    const float* src = (g == 0) ? bu : (g == 1) ? br : bc;
    xb[i] = src[j * 512 + n];
  }
}

// ============================================================================
extern "C" void kernel_launch(void* const* d_in, const int* in_sizes, int n_in,
                              void* d_out, int out_size, void* d_ws, size_t ws_size,
                              hipStream_t stream)
{
  const int*   tok = (const int*)  d_in[0];
  const float* vgg = (const float*)d_in[1];
  const float* emb = (const float*)d_in[2];
  const float* Win = (const float*)d_in[3];
  const float* bin = (const float*)d_in[4];
  const float* Wu  = (const float*)d_in[5];
  const float* bu  = (const float*)d_in[6];
  const float* Wr  = (const float*)d_in[7];
  const float* br  = (const float*)d_in[8];
  const float* Wc  = (const float*)d_in[9];
  const float* bc  = (const float*)d_in[10];
  const float* Wo  = (const float*)d_in[11];
  const float* bo  = (const float*)d_in[12];
  float* out = (float*)d_out;

  size_t off = 0;
  auto alloc = [&](size_t bytes) -> void* {
    void* p = (char*)d_ws + off;
    off += (bytes + 255) & ~(size_t)255;
    return p;
  };
  float*  hs0init = (float*) alloc(SLOT * 4);
  bf16_t* rh0s  = (bf16_t*)alloc(41 * SLOT * 2);
  bf16_t* rh1s  = (bf16_t*)alloc(41 * SLOT * 2);
  bf16_t* hb0_seq = (bf16_t*)alloc(41 * SLOT * 2);
  bf16_t* hb1_seq = (bf16_t*)alloc(41 * SLOT * 2);
  bf16_t* Aemb  = (bf16_t*)alloc((size_t)TT * BB * 512 * 2);
  float*  xg0   = (float*) alloc((size_t)TT * BB * 1536 * 4);
  bf16_t* Btx0  = (bf16_t*)alloc((size_t)1536 * 512 * 2);
  bf16_t* Btru0 = (bf16_t*)alloc((size_t)1024 * 512 * 2);
  bf16_t* Btc0  = (bf16_t*)alloc((size_t)512 * 512 * 2);
  bf16_t* Bt1ru = (bf16_t*)alloc((size_t)1024 * 1024 * 2);
  bf16_t* Btc1  = (bf16_t*)alloc((size_t)512 * 1024 * 2);
  bf16_t* Wto   = (bf16_t*)alloc((size_t)10112 * 512 * 2);
  bf16_t* Wint  = (bf16_t*)alloc((size_t)512 * 4096 * 2);
  bf16_t* vggb  = (bf16_t*)alloc((size_t)128 * 4096 * 2);
  float*  h0part= (float*) alloc(8 * SLOT * 4);
  float*  xbias = (float*) alloc(2 * 1536 * 4);
  unsigned* syncws = (unsigned*) alloc(NSYNCW * 4);
  if (off > ws_size) return;

  TJobs10 tj;
  tj.j[0] = { Wu,                Btx0,                512, 512 };
  tj.j[1] = { Wr,                Btx0 + 262144,       512, 512 };
  tj.j[2] = { Wc,                Btx0 + 524288,       512, 512 };
  tj.j[3] = { Wu + 262144,       Btru0,               512, 512 };
  tj.j[4] = { Wr + 262144,       Btru0 + 262144,      512, 512 };
  tj.j[5] = { Wc + 262144,       Btc0,                512, 512 };
  tj.j[6] = { Wu + 524288,       Bt1ru,               1024, 1024 };
  tj.j[7] = { Wr + 524288,       Bt1ru + 524288,      1024, 1024 };
  tj.j[8] = { Wc + 524288,       Btc1,                1024, 1024 };
  tj.j[9] = { Win,               Wint,                4096, 4096 };
  transpose_gen<<<dim3(128, 16, 10), dim3(32, 8), 0, stream>>>(tj);
  transpose_wout<<<dim3(16, 316), dim3(32, 8), 0, stream>>>(Wo, Wto);
  build_xbias<<<12, 256, 0, stream>>>(bu, br, bc, xbias);
  gather_emb<<<TT * BB, 128, 0, stream>>>(tok, emb, Aemb);
  conv_bf16<<<512, 256, 0, stream>>>(vgg, vggb);
  zero_sync<<<1, 256, 0, stream>>>(syncws);

  h0_gemm<<<dim3(4, 8), 256, 0, stream>>>(vggb, Wint, h0part);
  h0_fin<<<256, 256, 0, stream>>>(h0part, bin, hs0init, hb0_seq, hb1_seq);

  gemm_bt<<<dim3(40, 12), 256, 0, stream>>>(Aemb, Btx0, xbias, xg0, 1536, 1536, 0);

  PArgs pa;
  pa.Btru0 = Btru0; pa.Bt1ru = Bt1ru; pa.Btc0 = Btc0; pa.Btc1 = Btc1;
  pa.xg0 = xg0; pa.bu = bu; pa.br = br; pa.bc = bc; pa.hs0init = hs0init;
  pa.hb0_seq = hb0_seq; pa.hb1_seq = hb1_seq;
  pa.rh0s = rh0s; pa.rh1s = rh1s;
  pa.Wto = Wto; pa.bo = bo; pa.out = out;
  pa.out_hfin = out + (size_t)BB * TT * VV;
  pa.sync = syncws;
  gru_persist<<<NGRID, 256, 0, stream>>>(pa);
}

// Round 20
// 579.028 us; speedup vs baseline: 1.1374x; 1.0705x over previous
//
#include <hip/hip_runtime.h>
#include <hip/hip_bf16.h>
#include <math.h>

typedef __bf16 bf16_t;
typedef __bf16 bf16x8 __attribute__((ext_vector_type(8)));
typedef float  f32x4 __attribute__((ext_vector_type(4)));
typedef float  f4    __attribute__((ext_vector_type(4)));
typedef float  f2    __attribute__((ext_vector_type(2)));
typedef unsigned short u16x4 __attribute__((ext_vector_type(4)));
typedef unsigned long long u64;

#define HS  512
#define BB  128
#define TT  40
#define VV  10000
#define VGGN 4096
#define SLOT ((size_t)65536)   // 128*512
#define NBLK 96                // 2 pipelines x (16 L0 + 32 L1)
#define NGRID 256              // + 160 workers (xg pre-phase, then logits)

// Counter lines (u32 index; 64 u32 = 256B/line).
#define CL(h, idx) ((((h) * 164) + (idx)) * 64)
#define CRH0(h,s) CL(h, (s))
#define CHB0(h,s) CL(h, 41 + (s))
#define CRH1(h,s) CL(h, 82 + (s))
#define CHB1(h,s) CL(h, 123 + (s))
#define XGR(t)    ((328 + (t)) * 64)   // xg0 t-slice ready (target 12)
#define NSYNCW (368 * 64)

// ============================================================================
// Data-plane protocol (validated R12-R17): cross-block buffers are WRITE-ONCE
// slots; producers use agent-scope (L2-bypass) stores so L3 is current;
// consumers use PLAIN cached loads after the slot counter fires; entry
// __threadfence kills stale clean lines. u/h in registers (column-ownership).
// Two free-running 64-row pipelines (R17); xg hoisting (R19). R20: xg0 GEMM
// produced in-kernel by workers (XGR counters); prep micro-kernels merged.
// ============================================================================
__device__ __forceinline__ void cst64(void* p, u64 v) {
  __hip_atomic_store((u64*)p, v, __ATOMIC_RELAXED, __HIP_MEMORY_SCOPE_AGENT);
}
__device__ __forceinline__ void cst32(float* p, float v) {
  __hip_atomic_store(p, v, __ATOMIC_RELAXED, __HIP_MEMORY_SCOPE_AGENT);
}

__device__ __forceinline__ void slot_inc(unsigned* sync, int line)
{
  __syncthreads();                 // drain agent stores (vmcnt(0) at barrier)
  asm volatile("" ::: "memory");
  if (threadIdx.x == 0)
    __hip_atomic_fetch_add(&sync[line], 1u, __ATOMIC_RELAXED,
                           __HIP_MEMORY_SCOPE_AGENT);
}

template<int SLP>
__device__ __forceinline__ void slot_wait(unsigned* sync, int line,
                                          unsigned target)
{
  if (threadIdx.x == 0) {
    while (__hip_atomic_load(&sync[line], __ATOMIC_RELAXED,
                             __HIP_MEMORY_SCOPE_AGENT) < target)
      __builtin_amdgcn_s_sleep(SLP);
  }
  asm volatile("" ::: "memory");
  __syncthreads();
}

template<int SLP>
__device__ __forceinline__ void slot_wait2(unsigned* sync, int lineA,
                                           unsigned tA, int lineB, unsigned tB)
{
  if (threadIdx.x == 0) {
    while (__hip_atomic_load(&sync[lineA], __ATOMIC_RELAXED,
                             __HIP_MEMORY_SCOPE_AGENT) < tA)
      __builtin_amdgcn_s_sleep(SLP);
    while (__hip_atomic_load(&sync[lineB], __ATOMIC_RELAXED,
                             __HIP_MEMORY_SCOPE_AGENT) < tB)
      __builtin_amdgcn_s_sleep(SLP);
  }
  asm volatile("" ::: "memory");
  __syncthreads();
}

// ============================================================================
// Merged prep: zero_sync | build_xbias | conv_bf16 | gather_emb (one launch).
// ============================================================================
struct MiscArgs {
  unsigned* sync;
  const float *bu, *br, *bc;
  float* xbias;
  const float* vgg; bf16_t* vggb;
  const int* tok; const float* emb; bf16_t* Aemb;
};
__global__ __launch_bounds__(256) void prep_misc(MiscArgs M)
{
  const int b = blockIdx.x, tid = threadIdx.x;
  if (b == 0) {
    for (int i = tid; i < NSYNCW; i += 256) M.sync[i] = 0u;
  } else if (b < 13) {
    int i = (b - 1) * 256 + tid;
    if (i < 2 * 1536) {
      int j = i / 1536, qq = i % 1536;
      int g = qq >> 9, n = qq & 511;
      const float* src = (g == 0) ? M.bu : (g == 1) ? M.br : M.bc;
      M.xbias[i] = src[j * 512 + n];
    }
  } else if (b < 525) {
    int i = (b - 13) * 256 + tid;
    f4 v = ((const f4*)M.vgg)[i];
    M.vggb[i * 4 + 0] = (bf16_t)v[0]; M.vggb[i * 4 + 1] = (bf16_t)v[1];
    M.vggb[i * 4 + 2] = (bf16_t)v[2]; M.vggb[i * 4 + 3] = (bf16_t)v[3];
  } else {
    int blk = b - 525;                 // 0..2559, 2 rows each
    int m = blk * 2 + (tid >> 7);      // 0..5119
    int t = m >> 7, bb = m & 127;
    int tk = M.tok[bb * TT + t];
    int i = tid & 127;
    f4 v = *(const f4*)(M.emb + (size_t)tk * 512 + i * 4);
    bf16_t* dst = M.Aemb + (size_t)m * 512 + i * 4;
    dst[0] = (bf16_t)v[0]; dst[1] = (bf16_t)v[1];
    dst[2] = (bf16_t)v[2]; dst[3] = (bf16_t)v[3];
  }
}

// ============================================================================
// Dual-pipeline column-ownership persistent GRU + fused xg0 + fused logits.
// ============================================================================
struct PArgs {
  const bf16_t *Btru0, *Bt1ru, *Btc0, *Btc1;
  const float  *bu, *br, *bc, *hs0init;
  float *xg0;
  const bf16_t *Aemb, *Btx0;
  const float  *xbias;
  bf16_t *hb0_seq, *hb1_seq, *rh0s, *rh1s;
  const bf16_t *Wto;
  const float  *bo;
  float *out, *out_hfin;
  unsigned *sync;
};

template<int K, int NF>
__device__ __forceinline__ void tile_gemm64(
    const bf16_t* __restrict__ A0, const bf16_t* __restrict__ A1,
    const bf16_t* Bs, int wave, int lane, f32x4 (&acc)[NF])
{
  const int l15 = lane & 15, kg = lane >> 4;
  const int mw = wave * 16;
#pragma unroll
  for (int f = 0; f < NF; ++f)
#pragma unroll
    for (int e = 0; e < 4; ++e) acc[f][e] = 0.f;

#pragma unroll
  for (int kk = 0; kk < K; kk += 32) {
    const bf16_t* Asrc = (kk < 512) ? A0 : A1;
    const int kc = (kk < 512 ? kk : kk - 512) + kg * 8;
    bf16x8 a = *(const bf16x8*)(Asrc + (size_t)(mw + l15) * 512 + kc);
    bf16x8 b[NF];
#pragma unroll
    for (int f = 0; f < NF; ++f) {
      int row = f * 16 + l15;
      int byteoff = row * (2 * K) + ((2 * kk + 16 * kg) ^ ((row & 7) << 4));
      b[f] = *(const bf16x8*)((const char*)Bs + byteoff);
    }
#pragma unroll
    for (int f = 0; f < NF; ++f)
      acc[f] = __builtin_amdgcn_mfma_f32_16x16x32_bf16(a, b[f], acc[f], 0, 0, 0);
  }
}

template<int C>
__device__ __forceinline__ void publish64(
    bf16_t* dst, int row0, int n0, float (&v)[2][4],
    unsigned short (*tb)[36], int wave, int lane, int tid)
{
  const int l15 = lane & 15, kg = lane >> 4;
  const int mw = wave * 16;
  constexpr int NFp = C / 16;
#pragma unroll
  for (int f = 0; f < NFp; ++f)
#pragma unroll
    for (int e = 0; e < 4; ++e)
      tb[mw + kg * 4 + e][f * 16 + l15] =
          __builtin_bit_cast(unsigned short, (bf16_t)v[f][e]);
  __syncthreads();
  constexpr int NU = 64 * C / 4;        // u64 stores
  constexpr int IT = (NU + 255) / 256;
#pragma unroll
  for (int it = 0; it < IT; ++it) {
    int lin = it * 256 + tid;
    if (lin < NU) {
      int row = lin / (C / 4);
      int cc  = (lin % (C / 4)) * 4;
      u16x4 pk = { tb[row][cc], tb[row][cc + 1], tb[row][cc + 2], tb[row][cc + 3] };
      cst64(dst + (size_t)(row0 + row) * 512 + n0 + cc, __builtin_bit_cast(u64, pk));
    }
  }
}

__global__ __launch_bounds__(256) void gru_persist(PArgs P)
{
  const int bid = blockIdx.x, tid = threadIdx.x;
  const int wave = tid >> 6, lane = tid & 63;
  const int l15 = lane & 15, kg = lane >> 4;
  unsigned* sync = P.sync;

  __threadfence();
  __syncthreads();

  // ===================== worker blocks: xg0 pre-phase, then logits ========
  if (bid >= NBLK) {
    const int w = bid - NBLK;                 // 0..159
    const int wm = (wave >> 1) * 64, wn = (wave & 1) * 64;

    // ---- xg0 tiles (t-major; 480 tiles; agent stores + XGR counters) ----
    for (int tau = w; tau < TT * 12; tau += (NGRID - NBLK)) {
      const int t = tau / 12, nb = tau % 12;
      const int bm = t * 128, bn = nb * 128;
      const bf16_t* Ap = P.Aemb + (size_t)(bm + wm + l15) * 512 + kg * 8;
      const bf16_t* Bp = P.Btx0 + (size_t)(bn + wn + l15) * 512 + kg * 8;
      f32x4 acc[4][4];
#pragma unroll
      for (int i = 0; i < 4; ++i)
#pragma unroll
        for (int j = 0; j < 4; ++j)
#pragma unroll
          for (int e = 0; e < 4; ++e) acc[i][j][e] = 0.f;
      for (int kk = 0; kk < 512; kk += 32) {
        bf16x8 a[4], b[4];
#pragma unroll
        for (int i = 0; i < 4; ++i) a[i] = *(const bf16x8*)(Ap + (size_t)i * 16 * 512 + kk);
#pragma unroll
        for (int j = 0; j < 4; ++j) b[j] = *(const bf16x8*)(Bp + (size_t)j * 16 * 512 + kk);
#pragma unroll
        for (int i = 0; i < 4; ++i)
#pragma unroll
          for (int j = 0; j < 4; ++j)
            acc[i][j] = __builtin_amdgcn_mfma_f32_16x16x32_bf16(a[i], b[j], acc[i][j], 0, 0, 0);
      }
#pragma unroll
      for (int fm = 0; fm < 4; ++fm) {
#pragma unroll
        for (int fn = 0; fn < 4; ++fn) {
          int n = bn + wn + fn * 16 + l15;
          float bv = P.xbias[n];
#pragma unroll
          for (int e = 0; e < 4; ++e) {
            int m = bm + wm + fm * 16 + kg * 4 + e;
            cst32(&P.xg0[(size_t)m * 1536 + n], acc[fm][fn][e] + bv);
          }
        }
      }
      slot_inc(sync, XGR(t));
    }

    // ---- logits tiles ----
    for (int tau = w; tau < TT * 79; tau += (NGRID - NBLK)) {
      const int t = tau / 79, nb = tau % 79;
      slot_wait2<64>(sync, CHB1(0, t + 1), 32u, CHB1(1, t + 1), 32u);
      const bf16_t* A = P.hb1_seq + (size_t)(t + 1) * SLOT;
      const bf16_t* Bp = P.Wto + (size_t)(nb * 128 + wn + l15) * 512 + kg * 8;
      f32x4 acc[4][4];
#pragma unroll
      for (int i = 0; i < 4; ++i)
#pragma unroll
        for (int j = 0; j < 4; ++j)
#pragma unroll
          for (int e = 0; e < 4; ++e) acc[i][j][e] = 0.f;
      for (int kk = 0; kk < 512; kk += 32) {
        bf16x8 a[4], b[4];
#pragma unroll
        for (int i = 0; i < 4; ++i)
          a[i] = *(const bf16x8*)(A + (size_t)(wm + i * 16 + l15) * 512 + kk + kg * 8);
#pragma unroll
        for (int j = 0; j < 4; ++j)
          b[j] = *(const bf16x8*)(Bp + (size_t)j * 16 * 512 + kk);
#pragma unroll
        for (int i = 0; i < 4; ++i)
#pragma unroll
          for (int j = 0; j < 4; ++j)
            acc[i][j] = __builtin_amdgcn_mfma_f32_16x16x32_bf16(a[i], b[j], acc[i][j], 0, 0, 0);
      }
#pragma unroll
      for (int fm = 0; fm < 4; ++fm) {
#pragma unroll
        for (int fn = 0; fn < 4; ++fn) {
          int n = nb * 128 + wn + fn * 16 + l15;
          if (n >= VV) continue;
          float bv = P.bo[n];
#pragma unroll
          for (int e = 0; e < 4; ++e) {
            int b_row = wm + fm * 16 + kg * 4 + e;
            P.out[(size_t)(b_row * TT + t) * VV + n] = acc[fm][fn][e] + bv;
          }
        }
      }
      __syncthreads();
    }
    return;
  }

  // ===================== recurrence blocks ================================
  const int half = bid / 48;
  const int b2   = bid % 48;
  const int row0 = half * 64;
  const bool L0 = (b2 < 16);
  const int q  = L0 ? b2 : b2 - 16;
  const int n0 = L0 ? q * 32 : q * 16;
  const int mw = wave * 16;

  __shared__ bf16_t Bs[49152];                  // [RU 64KB | C 32KB]
  __shared__ unsigned short tb[64][36];
  bf16_t* BsRU = Bs;
  bf16_t* BsC  = Bs + 32768;

  if (L0) {
    for (int c = tid; c < 4096; c += 256) {
      int row = c >> 6, cb = (c & 63) * 16;
      const bf16_t* src = (row < 32) ? P.Btru0 + (size_t)(n0 + row) * 512
                                     : P.Btru0 + (size_t)(512 + n0 + row - 32) * 512;
      *(f4*)((char*)BsRU + row * 1024 + (cb ^ ((row & 7) << 4))) =
          *(const f4*)((const char*)src + cb);
    }
    for (int c = tid; c < 2048; c += 256) {
      int row = c >> 6, cb = (c & 63) * 16;
      const bf16_t* src = P.Btc0 + (size_t)(n0 + row) * 512;
      *(f4*)((char*)BsC + row * 1024 + (cb ^ ((row & 7) << 4))) =
          *(const f4*)((const char*)src + cb);
    }
  } else {
    for (int c = tid; c < 4096; c += 256) {
      int row = c >> 7, cb = (c & 127) * 16;
      const bf16_t* src = (row < 16) ? P.Bt1ru + (size_t)(n0 + row) * 1024
                                     : P.Bt1ru + (size_t)(512 + n0 + row - 16) * 1024;
      *(f4*)((char*)BsRU + row * 2048 + (cb ^ ((row & 7) << 4))) =
          *(const f4*)((const char*)src + cb);
    }
    for (int c = tid; c < 2048; c += 256) {
      int row = c >> 7, cb = (c & 127) * 16;
      const bf16_t* src = P.Btc1 + (size_t)(n0 + row) * 1024;
      *(f4*)((char*)BsC + row * 2048 + (cb ^ ((row & 7) << 4))) =
          *(const f4*)((const char*)src + cb);
    }
  }
  __syncthreads();

  const int NFh = L0 ? 2 : 1;
  float hreg[2][4], ureg[2][4], rhv[2][4];
#pragma unroll
  for (int f = 0; f < 2; ++f)
#pragma unroll
    for (int e = 0; e < 4; ++e) {
      int row = row0 + mw + kg * 4 + e;
      hreg[f][e] = (f < NFh)
          ? P.hs0init[(size_t)row * 512 + n0 + f * 16 + l15] : 0.f;
      ureg[f][e] = 0.f; rhv[f][e] = 0.f;
    }

  if (L0) {
    for (int s = 0; s < 40; ++s) {
      slot_wait<8>(sync, XGR(s), 12u);          // xg0 slice ready (fast)
      const float* xg = P.xg0 + (size_t)s * 128 * 1536;
      float xvu[2][4], xvr[2][4];
#pragma unroll
      for (int f = 0; f < 2; ++f)
#pragma unroll
        for (int e = 0; e < 4; ++e) {
          int row = row0 + mw + kg * 4 + e;
          int col = n0 + f * 16 + l15;
          xvu[f][e] = xg[(size_t)row * 1536 + col];
          xvr[f][e] = xg[(size_t)row * 1536 + 512 + col];
        }
      if (s >= 1) slot_wait<8>(sync, CHB0(half, s), 16u);
      f32x4 acc4[4];
      const bf16_t* A0 = P.hb0_seq + (size_t)s * SLOT + (size_t)row0 * 512;
      tile_gemm64<512, 4>(A0, A0, BsRU, wave, lane, acc4);
#pragma unroll
      for (int f = 0; f < 2; ++f)
#pragma unroll
        for (int e = 0; e < 4; ++e) {
          float pu = acc4[f][e]     + xvu[f][e];
          float pr = acc4[f + 2][e] + xvr[f][e];
          ureg[f][e] = 1.f / (1.f + expf(-pu));
          rhv[f][e]  = (1.f / (1.f + expf(-pr))) * hreg[f][e];
        }
      publish64<32>(P.rh0s + (size_t)s * SLOT, row0, n0, rhv, tb, wave, lane, tid);
      slot_inc(sync, CRH0(half, s));
      float xvc[2][4];
#pragma unroll
      for (int f = 0; f < 2; ++f)
#pragma unroll
        for (int e = 0; e < 4; ++e) {
          int row = row0 + mw + kg * 4 + e;
          int col = n0 + f * 16 + l15;
          xvc[f][e] = xg[(size_t)row * 1536 + 1024 + col];
        }
      slot_wait<8>(sync, CRH0(half, s), 16u);

      f32x4 acc2[2];
      const bf16_t* Arh = P.rh0s + (size_t)s * SLOT + (size_t)row0 * 512;
      tile_gemm64<512, 2>(Arh, Arh, BsC, wave, lane, acc2);
#pragma unroll
      for (int f = 0; f < 2; ++f)
#pragma unroll
        for (int e = 0; e < 4; ++e) {
          float c = tanhf(acc2[f][e] + xvc[f][e]);
          float u = ureg[f][e];
          hreg[f][e] = u * hreg[f][e] + (1.f - u) * c;
          rhv[f][e] = hreg[f][e];
        }
      publish64<32>(P.hb0_seq + (size_t)(s + 1) * SLOT, row0, n0, rhv, tb, wave, lane, tid);
      slot_inc(sync, CHB0(half, s + 1));
    }
  } else {
    const float bvu = P.bu[512 + n0 + l15];
    const float bvr = P.br[512 + n0 + l15];
    const float bvc = P.bc[512 + n0 + l15];
    for (int s = 1; s <= 40; ++s) {
      if (s >= 2) slot_wait2<8>(sync, CHB0(half, s), 16u, CHB1(half, s - 1), 32u);
      else        slot_wait<8>(sync, CHB0(half, 1), 16u);
      f32x4 acc2[2];
      tile_gemm64<1024, 2>(P.hb0_seq + (size_t)s * SLOT + (size_t)row0 * 512,
                           P.hb1_seq + (size_t)(s - 1) * SLOT + (size_t)row0 * 512,
                           BsRU, wave, lane, acc2);
#pragma unroll
      for (int e = 0; e < 4; ++e) {
        float pu = acc2[0][e] + bvu;
        float pr = acc2[1][e] + bvr;
        ureg[0][e] = 1.f / (1.f + expf(-pu));
        rhv[0][e]  = (1.f / (1.f + expf(-pr))) * hreg[0][e];
      }
      publish64<16>(P.rh1s + (size_t)s * SLOT, row0, n0, rhv, tb, wave, lane, tid);
      slot_inc(sync, CRH1(half, s));
      slot_wait<8>(sync, CRH1(half, s), 32u);

      f32x4 acc1[1];
      tile_gemm64<1024, 1>(P.hb0_seq + (size_t)s * SLOT + (size_t)row0 * 512,
                           P.rh1s + (size_t)s * SLOT + (size_t)row0 * 512,
                           BsC, wave, lane, acc1);
#pragma unroll
      for (int e = 0; e < 4; ++e) {
        float c = tanhf(acc1[0][e] + bvc);
        float u = ureg[0][e];
        hreg[0][e] = u * hreg[0][e] + (1.f - u) * c;
        rhv[0][e] = hreg[0][e];
      }
      publish64<16>(P.hb1_seq + (size_t)s * SLOT, row0, n0, rhv, tb, wave, lane, tid);
      slot_inc(sync, CHB1(half, s));
    }
  }

  float* dst = P.out_hfin + (L0 ? 0 : 65536);
#pragma unroll
  for (int f = 0; f < 2; ++f)
    if (f < NFh)
#pragma unroll
      for (int e = 0; e < 4; ++e) {
        int row = row0 + mw + kg * 4 + e;
        dst[(size_t)row * 512 + n0 + f * 16 + l15] = hreg[f][e];
      }
}

// ============================================================================
// h0 = tanh(vgg @ W_in + b_in) via bf16 MFMA, split-K=8.
// ============================================================================
__global__ __launch_bounds__(256) void h0_gemm(
    const bf16_t* __restrict__ vggb, const bf16_t* __restrict__ Wint,
    float* __restrict__ part)
{
  const int bn = blockIdx.x * 128, z = blockIdx.y, k0 = z * 512;
  const int tid = threadIdx.x;
  const int wave = tid >> 6, lane = tid & 63;
  const int wm = (wave >> 1) * 64, wn = (wave & 1) * 64;
  const int l15 = lane & 15, kg = lane >> 4;
  const bf16_t* Ap = vggb + (size_t)(wm + l15) * 4096 + k0 + kg * 8;
  const bf16_t* Bp = Wint + (size_t)(bn + wn + l15) * 4096 + k0 + kg * 8;
  f32x4 acc[4][4];
#pragma unroll
  for (int i = 0; i < 4; ++i)
#pragma unroll
    for (int j = 0; j < 4; ++j)
#pragma unroll
      for (int e = 0; e < 4; ++e) acc[i][j][e] = 0.f;
  for (int kk = 0; kk < 512; kk += 32) {
    bf16x8 a[4], b[4];
#pragma unroll
    for (int i = 0; i < 4; ++i) a[i] = *(const bf16x8*)(Ap + (size_t)i * 16 * 4096 + kk);
#pragma unroll
    for (int j = 0; j < 4; ++j) b[j] = *(const bf16x8*)(Bp + (size_t)j * 16 * 4096 + kk);
#pragma unroll
    for (int i = 0; i < 4; ++i)
#pragma unroll
      for (int j = 0; j < 4; ++j)
        acc[i][j] = __builtin_amdgcn_mfma_f32_16x16x32_bf16(a[i], b[j], acc[i][j], 0, 0, 0);
  }
#pragma unroll
  for (int fm = 0; fm < 4; ++fm)
#pragma unroll
    for (int fn = 0; fn < 4; ++fn) {
      int n = bn + wn + fn * 16 + l15;
#pragma unroll
      for (int e = 0; e < 4; ++e) {
        int m = wm + fm * 16 + kg * 4 + e;
        part[(size_t)z * SLOT + m * 512 + n] = acc[fm][fn][e];
      }
    }
}

__global__ void h0_fin(const float* __restrict__ part, const float* __restrict__ bin,
                       float* __restrict__ hs0init,
                       bf16_t* __restrict__ hb00, bf16_t* __restrict__ hb10)
{
  int i = blockIdx.x * 256 + threadIdx.x;   // 65536
  int n = i & 511;
  float s = bin[n];
#pragma unroll
  for (int z = 0; z < 8; ++z) s += part[(size_t)z * SLOT + i];
  float v = tanhf(s);
  hs0init[i] = v;
  hb00[i] = (bf16_t)v; hb10[i] = (bf16_t)v;
}

struct TJob { const float* src; bf16_t* dst; int K; int dstld; };
struct TJobs4 { TJob j[4]; };
__global__ void transpose_gen(TJobs4 jobs)
{
  TJob jb = jobs.j[blockIdx.z];
  int k0 = blockIdx.x * 32;
  if (k0 >= jb.K) return;
  int n0 = blockIdx.y * 32;
  __shared__ float tile[32][33];
  int tx = threadIdx.x, ty = threadIdx.y;
#pragma unroll
  for (int r = 0; r < 4; ++r)
    tile[ty + 8 * r][tx] = jb.src[(size_t)(k0 + ty + 8 * r) * 512 + n0 + tx];
  __syncthreads();
#pragma unroll
  for (int r = 0; r < 4; ++r)
    jb.dst[(size_t)(n0 + ty + 8 * r) * jb.dstld + k0 + tx] = (bf16_t)tile[tx][ty + 8 * r];
}

struct TJobs6 { TJob j[6]; };
__global__ void transpose_gen6(TJobs6 jobs)
{
  TJob jb = jobs.j[blockIdx.z];
  int k0 = blockIdx.x * 32;
  if (k0 >= jb.K) return;
  int n0 = blockIdx.y * 32;
  __shared__ float tile[32][33];
  int tx = threadIdx.x, ty = threadIdx.y;
#pragma unroll
  for (int r = 0; r < 4; ++r)
    tile[ty + 8 * r][tx] = jb.src[(size_t)(k0 + ty + 8 * r) * 512 + n0 + tx];
  __syncthreads();
#pragma unroll
  for (int r = 0; r < 4; ++r)
    jb.dst[(size_t)(n0 + ty + 8 * r) * jb.dstld + k0 + tx] = (bf16_t)tile[tx][ty + 8 * r];
}

__global__ void transpose_wout(const float* __restrict__ W, bf16_t* __restrict__ dst)
{
  __shared__ float tile[32][33];
  int k0 = blockIdx.x * 32, n0 = blockIdx.y * 32;
  int tx = threadIdx.x, ty = threadIdx.y;
#pragma unroll
  for (int r = 0; r < 4; ++r) {
    int n = n0 + tx;
    tile[ty + 8 * r][tx] = (n < VV) ? W[(size_t)(k0 + ty + 8 * r) * VV + n] : 0.f;
  }
  __syncthreads();
#pragma unroll
  for (int r = 0; r < 4; ++r)
    dst[(size_t)(n0 + ty + 8 * r) * 512 + k0 + tx] = (bf16_t)tile[tx][ty + 8 * r];
}

// ============================================================================
extern "C" void kernel_launch(void* const* d_in, const int* in_sizes, int n_in,
                              void* d_out, int out_size, void* d_ws, size_t ws_size,
                              hipStream_t stream)
{
  const int*   tok = (const int*)  d_in[0];
  const float* vgg = (const float*)d_in[1];
  const float* emb = (const float*)d_in[2];
  const float* Win = (const float*)d_in[3];
  const float* bin = (const float*)d_in[4];
  const float* Wu  = (const float*)d_in[5];
  const float* bu  = (const float*)d_in[6];
  const float* Wr  = (const float*)d_in[7];
  const float* br  = (const float*)d_in[8];
  const float* Wc  = (const float*)d_in[9];
  const float* bc  = (const float*)d_in[10];
  const float* Wo  = (const float*)d_in[11];
  const float* bo  = (const float*)d_in[12];
  float* out = (float*)d_out;

  size_t off = 0;
  auto alloc = [&](size_t bytes) -> void* {
    void* p = (char*)d_ws + off;
    off += (bytes + 255) & ~(size_t)255;
    return p;
  };
  float*  hs0init = (float*) alloc(SLOT * 4);
  bf16_t* rh0s  = (bf16_t*)alloc(41 * SLOT * 2);
  bf16_t* rh1s  = (bf16_t*)alloc(41 * SLOT * 2);
  bf16_t* hb0_seq = (bf16_t*)alloc(41 * SLOT * 2);
  bf16_t* hb1_seq = (bf16_t*)alloc(41 * SLOT * 2);
  bf16_t* Aemb  = (bf16_t*)alloc((size_t)TT * BB * 512 * 2);
  float*  xg0   = (float*) alloc((size_t)TT * BB * 1536 * 4);
  bf16_t* Btx0  = (bf16_t*)alloc((size_t)1536 * 512 * 2);
  bf16_t* Btru0 = (bf16_t*)alloc((size_t)1024 * 512 * 2);
  bf16_t* Btc0  = (bf16_t*)alloc((size_t)512 * 512 * 2);
  bf16_t* Bt1ru = (bf16_t*)alloc((size_t)1024 * 1024 * 2);
  bf16_t* Btc1  = (bf16_t*)alloc((size_t)512 * 1024 * 2);
  bf16_t* Wto   = (bf16_t*)alloc((size_t)10112 * 512 * 2);
  bf16_t* Wint  = (bf16_t*)alloc((size_t)512 * 4096 * 2);
  bf16_t* vggb  = (bf16_t*)alloc((size_t)128 * 4096 * 2);
  float*  h0part= (float*) alloc(8 * SLOT * 4);
  float*  xbias = (float*) alloc(2 * 1536 * 4);
  unsigned* syncws = (unsigned*) alloc(NSYNCW * 4);
  if (off > ws_size) return;

  // ---- merged misc prep (zero_sync | xbias | vgg->bf16 | emb gather) ----
  MiscArgs ma;
  ma.sync = syncws; ma.bu = bu; ma.br = br; ma.bc = bc; ma.xbias = xbias;
  ma.vgg = vgg; ma.vggb = vggb; ma.tok = tok; ma.emb = emb; ma.Aemb = Aemb;
  prep_misc<<<3085, 256, 0, stream>>>(ma);

  // ---- weight transposes ----
  TJobs4 t4;
  t4.j[0] = { Wu,          Btx0,           512, 512 };
  t4.j[1] = { Wr,          Btx0 + 262144,  512, 512 };
  t4.j[2] = { Wc,          Btx0 + 524288,  512, 512 };
  t4.j[3] = { Win,         Wint,           4096, 4096 };
  transpose_gen<<<dim3(128, 16, 4), dim3(32, 8), 0, stream>>>(t4);
  TJobs6 t6;
  t6.j[0] = { Wu + 262144, Btru0,            512, 512 };
  t6.j[1] = { Wr + 262144, Btru0 + 262144,   512, 512 };
  t6.j[2] = { Wc + 262144, Btc0,             512, 512 };
  t6.j[3] = { Wu + 524288, Bt1ru,            1024, 1024 };
  t6.j[4] = { Wr + 524288, Bt1ru + 524288,   1024, 1024 };
  t6.j[5] = { Wc + 524288, Btc1,             1024, 1024 };
  transpose_gen6<<<dim3(32, 16, 6), dim3(32, 8), 0, stream>>>(t6);
  transpose_wout<<<dim3(16, 316), dim3(32, 8), 0, stream>>>(Wo, Wto);

  // ---- h0 init ----
  h0_gemm<<<dim3(4, 8), 256, 0, stream>>>(vggb, Wint, h0part);
  h0_fin<<<256, 256, 0, stream>>>(h0part, bin, hs0init, hb0_seq, hb1_seq);

  // ---- persistent fused kernel (xg0 + recurrence + logits) ----
  PArgs pa;
  pa.Btru0 = Btru0; pa.Bt1ru = Bt1ru; pa.Btc0 = Btc0; pa.Btc1 = Btc1;
  pa.bu = bu; pa.br = br; pa.bc = bc; pa.hs0init = hs0init;
  pa.xg0 = xg0; pa.Aemb = Aemb; pa.Btx0 = Btx0; pa.xbias = xbias;
  pa.hb0_seq = hb0_seq; pa.hb1_seq = hb1_seq;
  pa.rh0s = rh0s; pa.rh1s = rh1s;
  pa.Wto = Wto; pa.bo = bo; pa.out = out;
  pa.out_hfin = out + (size_t)BB * TT * VV;
  pa.sync = syncws;
  gru_persist<<<NGRID, 256, 0, stream>>>(pa);
}

// Round 21
// 532.615 us; speedup vs baseline: 1.2365x; 1.0871x over previous
//
#include <hip/hip_runtime.h>
#include <hip/hip_bf16.h>
#include <math.h>

typedef __bf16 bf16_t;
typedef __bf16 bf16x8 __attribute__((ext_vector_type(8)));
typedef float  f32x4 __attribute__((ext_vector_type(4)));
typedef float  f4    __attribute__((ext_vector_type(4)));
typedef float  f2    __attribute__((ext_vector_type(2)));
typedef unsigned short u16x4 __attribute__((ext_vector_type(4)));
typedef unsigned long long u64;

#define HS  512
#define BB  128
#define TT  40
#define VV  10000
#define VGGN 4096
#define SLOT ((size_t)65536)   // 128*512
#define NBLK 96                // 2 pipelines x (16 L0 + 32 L1)
#define NGRID 256              // + 160 workers (xg pre-phase, then logits)

// Counter lines (u32 index; 64 u32 = 256B/line).
#define CL(h, idx) ((((h) * 164) + (idx)) * 64)
#define CRH0(h,s) CL(h, (s))
#define CHB0(h,s) CL(h, 41 + (s))
#define CRH1(h,s) CL(h, 82 + (s))
#define CHB1(h,s) CL(h, 123 + (s))
#define XGR(t)    ((328 + (t)) * 64)   // xg0 t-slice ready (target 12)
#define NSYNCW (368 * 64)

// ============================================================================
// Data-plane protocol (validated R12-R17): cross-block buffers are WRITE-ONCE
// slots; producers use agent-scope (L2-bypass) stores so L3 is current;
// consumers use PLAIN cached loads after the slot counter fires; entry
// __threadfence kills stale clean lines. u/h in registers (column-ownership).
// Two free-running 64-row pipelines (R17); xg hoisting (R19); in-kernel xg0 +
// merged prep (R20). R21: L1 links split-K around the waits — the hb0-halves
// of RU1/C1 (independent of the critical hb1/rh1 operands) are precomputed
// before the critical wait, halving the GEMM work on the serial chain.
// Summation order unchanged -> bitwise-identical results.
// ============================================================================
__device__ __forceinline__ void cst64(void* p, u64 v) {
  __hip_atomic_store((u64*)p, v, __ATOMIC_RELAXED, __HIP_MEMORY_SCOPE_AGENT);
}
__device__ __forceinline__ void cst32(float* p, float v) {
  __hip_atomic_store(p, v, __ATOMIC_RELAXED, __HIP_MEMORY_SCOPE_AGENT);
}

__device__ __forceinline__ void slot_inc(unsigned* sync, int line)
{
  __syncthreads();                 // drain agent stores (vmcnt(0) at barrier)
  asm volatile("" ::: "memory");
  if (threadIdx.x == 0)
    __hip_atomic_fetch_add(&sync[line], 1u, __ATOMIC_RELAXED,
                           __HIP_MEMORY_SCOPE_AGENT);
}

template<int SLP>
__device__ __forceinline__ void slot_wait(unsigned* sync, int line,
                                          unsigned target)
{
  if (threadIdx.x == 0) {
    while (__hip_atomic_load(&sync[line], __ATOMIC_RELAXED,
                             __HIP_MEMORY_SCOPE_AGENT) < target)
      __builtin_amdgcn_s_sleep(SLP);
  }
  asm volatile("" ::: "memory");
  __syncthreads();
}

template<int SLP>
__device__ __forceinline__ void slot_wait2(unsigned* sync, int lineA,
                                           unsigned tA, int lineB, unsigned tB)
{
  if (threadIdx.x == 0) {
    while (__hip_atomic_load(&sync[lineA], __ATOMIC_RELAXED,
                             __HIP_MEMORY_SCOPE_AGENT) < tA)
      __builtin_amdgcn_s_sleep(SLP);
    while (__hip_atomic_load(&sync[lineB], __ATOMIC_RELAXED,
                             __HIP_MEMORY_SCOPE_AGENT) < tB)
      __builtin_amdgcn_s_sleep(SLP);
  }
  asm volatile("" ::: "memory");
  __syncthreads();
}

// ============================================================================
// Merged prep: zero_sync | build_xbias | conv_bf16 | gather_emb (one launch).
// ============================================================================
struct MiscArgs {
  unsigned* sync;
  const float *bu, *br, *bc;
  float* xbias;
  const float* vgg; bf16_t* vggb;
  const int* tok; const float* emb; bf16_t* Aemb;
};
__global__ __launch_bounds__(256) void prep_misc(MiscArgs M)
{
  const int b = blockIdx.x, tid = threadIdx.x;
  if (b == 0) {
    for (int i = tid; i < NSYNCW; i += 256) M.sync[i] = 0u;
  } else if (b < 13) {
    int i = (b - 1) * 256 + tid;
    if (i < 2 * 1536) {
      int j = i / 1536, qq = i % 1536;
      int g = qq >> 9, n = qq & 511;
      const float* src = (g == 0) ? M.bu : (g == 1) ? M.br : M.bc;
      M.xbias[i] = src[j * 512 + n];
    }
  } else if (b < 525) {
    int i = (b - 13) * 256 + tid;
    f4 v = ((const f4*)M.vgg)[i];
    M.vggb[i * 4 + 0] = (bf16_t)v[0]; M.vggb[i * 4 + 1] = (bf16_t)v[1];
    M.vggb[i * 4 + 2] = (bf16_t)v[2]; M.vggb[i * 4 + 3] = (bf16_t)v[3];
  } else {
    int blk = b - 525;                 // 0..2559, 2 rows each
    int m = blk * 2 + (tid >> 7);      // 0..5119
    int t = m >> 7, bb = m & 127;
    int tk = M.tok[bb * TT + t];
    int i = tid & 127;
    f4 v = *(const f4*)(M.emb + (size_t)tk * 512 + i * 4);
    bf16_t* dst = M.Aemb + (size_t)m * 512 + i * 4;
    dst[0] = (bf16_t)v[0]; dst[1] = (bf16_t)v[1];
    dst[2] = (bf16_t)v[2]; dst[3] = (bf16_t)v[3];
  }
}

// ============================================================================
// Dual-pipeline column-ownership persistent GRU + fused xg0 + fused logits.
// ============================================================================
struct PArgs {
  const bf16_t *Btru0, *Bt1ru, *Btc0, *Btc1;
  const float  *bu, *br, *bc, *hs0init;
  float *xg0;
  const bf16_t *Aemb, *Btx0;
  const float  *xbias;
  bf16_t *hb0_seq, *hb1_seq, *rh0s, *rh1s;
  const bf16_t *Wto;
  const float  *bo;
  float *out, *out_hfin;
  unsigned *sync;
};

// 64-row GEMM over K (L0, row stride 2*K bytes in LDS B).
template<int K, int NF>
__device__ __forceinline__ void tile_gemm64(
    const bf16_t* __restrict__ A0, const bf16_t* __restrict__ A1,
    const bf16_t* Bs, int wave, int lane, f32x4 (&acc)[NF])
{
  const int l15 = lane & 15, kg = lane >> 4;
  const int mw = wave * 16;
#pragma unroll
  for (int f = 0; f < NF; ++f)
#pragma unroll
    for (int e = 0; e < 4; ++e) acc[f][e] = 0.f;

#pragma unroll
  for (int kk = 0; kk < K; kk += 32) {
    const bf16_t* Asrc = (kk < 512) ? A0 : A1;
    const int kc = (kk < 512 ? kk : kk - 512) + kg * 8;
    bf16x8 a = *(const bf16x8*)(Asrc + (size_t)(mw + l15) * 512 + kc);
    bf16x8 b[NF];
#pragma unroll
    for (int f = 0; f < NF; ++f) {
      int row = f * 16 + l15;
      int byteoff = row * (2 * K) + ((2 * kk + 16 * kg) ^ ((row & 7) << 4));
      b[f] = *(const bf16x8*)((const char*)Bs + byteoff);
    }
#pragma unroll
    for (int f = 0; f < NF; ++f)
      acc[f] = __builtin_amdgcn_mfma_f32_16x16x32_bf16(a, b[f], acc[f], 0, 0, 0);
  }
}

// 64-row K=512 half-GEMM for L1 (LDS B row stride 2048B; koff selects the
// K-half of the weight rows). ACC=false zeroes, true accumulates.
template<int NF, bool ACC>
__device__ __forceinline__ void tile_gemm64_h(
    const bf16_t* __restrict__ A, const bf16_t* Bs, int koff,
    int wave, int lane, f32x4 (&acc)[NF])
{
  const int l15 = lane & 15, kg = lane >> 4;
  const int mw = wave * 16;
  if (!ACC) {
#pragma unroll
    for (int f = 0; f < NF; ++f)
#pragma unroll
      for (int e = 0; e < 4; ++e) acc[f][e] = 0.f;
  }
#pragma unroll
  for (int kk = 0; kk < 512; kk += 32) {
    bf16x8 a = *(const bf16x8*)(A + (size_t)(mw + l15) * 512 + kk + kg * 8);
    bf16x8 b[NF];
#pragma unroll
    for (int f = 0; f < NF; ++f) {
      int row = f * 16 + l15;
      int byteoff = row * 2048 + ((2 * (koff + kk) + 16 * kg) ^ ((row & 7) << 4));
      b[f] = *(const bf16x8*)((const char*)Bs + byteoff);
    }
#pragma unroll
    for (int f = 0; f < NF; ++f)
      acc[f] = __builtin_amdgcn_mfma_f32_16x16x32_bf16(a, b[f], acc[f], 0, 0, 0);
  }
}

template<int C>
__device__ __forceinline__ void publish64(
    bf16_t* dst, int row0, int n0, float (&v)[2][4],
    unsigned short (*tb)[36], int wave, int lane, int tid)
{
  const int l15 = lane & 15, kg = lane >> 4;
  const int mw = wave * 16;
  constexpr int NFp = C / 16;
#pragma unroll
  for (int f = 0; f < NFp; ++f)
#pragma unroll
    for (int e = 0; e < 4; ++e)
      tb[mw + kg * 4 + e][f * 16 + l15] =
          __builtin_bit_cast(unsigned short, (bf16_t)v[f][e]);
  __syncthreads();
  constexpr int NU = 64 * C / 4;        // u64 stores
  constexpr int IT = (NU + 255) / 256;
#pragma unroll
  for (int it = 0; it < IT; ++it) {
    int lin = it * 256 + tid;
    if (lin < NU) {
      int row = lin / (C / 4);
      int cc  = (lin % (C / 4)) * 4;
      u16x4 pk = { tb[row][cc], tb[row][cc + 1], tb[row][cc + 2], tb[row][cc + 3] };
      cst64(dst + (size_t)(row0 + row) * 512 + n0 + cc, __builtin_bit_cast(u64, pk));
    }
  }
}

__global__ __launch_bounds__(256) void gru_persist(PArgs P)
{
  const int bid = blockIdx.x, tid = threadIdx.x;
  const int wave = tid >> 6, lane = tid & 63;
  const int l15 = lane & 15, kg = lane >> 4;
  unsigned* sync = P.sync;

  __threadfence();
  __syncthreads();

  // ===================== worker blocks: xg0 pre-phase, then logits ========
  if (bid >= NBLK) {
    const int w = bid - NBLK;                 // 0..159
    const int wm = (wave >> 1) * 64, wn = (wave & 1) * 64;

    // ---- xg0 tiles (t-major; 480 tiles; agent stores + XGR counters) ----
    for (int tau = w; tau < TT * 12; tau += (NGRID - NBLK)) {
      const int t = tau / 12, nb = tau % 12;
      const int bm = t * 128, bn = nb * 128;
      const bf16_t* Ap = P.Aemb + (size_t)(bm + wm + l15) * 512 + kg * 8;
      const bf16_t* Bp = P.Btx0 + (size_t)(bn + wn + l15) * 512 + kg * 8;
      f32x4 acc[4][4];
#pragma unroll
      for (int i = 0; i < 4; ++i)
#pragma unroll
        for (int j = 0; j < 4; ++j)
#pragma unroll
          for (int e = 0; e < 4; ++e) acc[i][j][e] = 0.f;
      for (int kk = 0; kk < 512; kk += 32) {
        bf16x8 a[4], b[4];
#pragma unroll
        for (int i = 0; i < 4; ++i) a[i] = *(const bf16x8*)(Ap + (size_t)i * 16 * 512 + kk);
#pragma unroll
        for (int j = 0; j < 4; ++j) b[j] = *(const bf16x8*)(Bp + (size_t)j * 16 * 512 + kk);
#pragma unroll
        for (int i = 0; i < 4; ++i)
#pragma unroll
          for (int j = 0; j < 4; ++j)
            acc[i][j] = __builtin_amdgcn_mfma_f32_16x16x32_bf16(a[i], b[j], acc[i][j], 0, 0, 0);
      }
#pragma unroll
      for (int fm = 0; fm < 4; ++fm) {
#pragma unroll
        for (int fn = 0; fn < 4; ++fn) {
          int n = bn + wn + fn * 16 + l15;
          float bv = P.xbias[n];
#pragma unroll
          for (int e = 0; e < 4; ++e) {
            int m = bm + wm + fm * 16 + kg * 4 + e;
            cst32(&P.xg0[(size_t)m * 1536 + n], acc[fm][fn][e] + bv);
          }
        }
      }
      slot_inc(sync, XGR(t));
    }

    // ---- logits tiles ----
    for (int tau = w; tau < TT * 79; tau += (NGRID - NBLK)) {
      const int t = tau / 79, nb = tau % 79;
      slot_wait2<64>(sync, CHB1(0, t + 1), 32u, CHB1(1, t + 1), 32u);
      const bf16_t* A = P.hb1_seq + (size_t)(t + 1) * SLOT;
      const bf16_t* Bp = P.Wto + (size_t)(nb * 128 + wn + l15) * 512 + kg * 8;
      f32x4 acc[4][4];
#pragma unroll
      for (int i = 0; i < 4; ++i)
#pragma unroll
        for (int j = 0; j < 4; ++j)
#pragma unroll
          for (int e = 0; e < 4; ++e) acc[i][j][e] = 0.f;
      for (int kk = 0; kk < 512; kk += 32) {
        bf16x8 a[4], b[4];
#pragma unroll
        for (int i = 0; i < 4; ++i)
          a[i] = *(const bf16x8*)(A + (size_t)(wm + i * 16 + l15) * 512 + kk + kg * 8);
#pragma unroll
        for (int j = 0; j < 4; ++j)
          b[j] = *(const bf16x8*)(Bp + (size_t)j * 16 * 512 + kk);
#pragma unroll
        for (int i = 0; i < 4; ++i)
#pragma unroll
          for (int j = 0; j < 4; ++j)
            acc[i][j] = __builtin_amdgcn_mfma_f32_16x16x32_bf16(a[i], b[j], acc[i][j], 0, 0, 0);
      }
#pragma unroll
      for (int fm = 0; fm < 4; ++fm) {
#pragma unroll
        for (int fn = 0; fn < 4; ++fn) {
          int n = nb * 128 + wn + fn * 16 + l15;
          if (n >= VV) continue;
          float bv = P.bo[n];
#pragma unroll
          for (int e = 0; e < 4; ++e) {
            int b_row = wm + fm * 16 + kg * 4 + e;
            P.out[(size_t)(b_row * TT + t) * VV + n] = acc[fm][fn][e] + bv;
          }
        }
      }
      __syncthreads();
    }
    return;
  }

  // ===================== recurrence blocks ================================
  const int half = bid / 48;
  const int b2   = bid % 48;
  const int row0 = half * 64;
  const bool L0 = (b2 < 16);
  const int q  = L0 ? b2 : b2 - 16;
  const int n0 = L0 ? q * 32 : q * 16;
  const int mw = wave * 16;

  __shared__ bf16_t Bs[49152];                  // [RU 64KB | C 32KB]
  __shared__ unsigned short tb[64][36];
  bf16_t* BsRU = Bs;
  bf16_t* BsC  = Bs + 32768;

  if (L0) {
    for (int c = tid; c < 4096; c += 256) {
      int row = c >> 6, cb = (c & 63) * 16;
      const bf16_t* src = (row < 32) ? P.Btru0 + (size_t)(n0 + row) * 512
                                     : P.Btru0 + (size_t)(512 + n0 + row - 32) * 512;
      *(f4*)((char*)BsRU + row * 1024 + (cb ^ ((row & 7) << 4))) =
          *(const f4*)((const char*)src + cb);
    }
    for (int c = tid; c < 2048; c += 256) {
      int row = c >> 6, cb = (c & 63) * 16;
      const bf16_t* src = P.Btc0 + (size_t)(n0 + row) * 512;
      *(f4*)((char*)BsC + row * 1024 + (cb ^ ((row & 7) << 4))) =
          *(const f4*)((const char*)src + cb);
    }
  } else {
    for (int c = tid; c < 4096; c += 256) {
      int row = c >> 7, cb = (c & 127) * 16;
      const bf16_t* src = (row < 16) ? P.Bt1ru + (size_t)(n0 + row) * 1024
                                     : P.Bt1ru + (size_t)(512 + n0 + row - 16) * 1024;
      *(f4*)((char*)BsRU + row * 2048 + (cb ^ ((row & 7) << 4))) =
          *(const f4*)((const char*)src + cb);
    }
    for (int c = tid; c < 2048; c += 256) {
      int row = c >> 7, cb = (c & 127) * 16;
      const bf16_t* src = P.Btc1 + (size_t)(n0 + row) * 1024;
      *(f4*)((char*)BsC + row * 2048 + (cb ^ ((row & 7) << 4))) =
          *(const f4*)((const char*)src + cb);
    }
  }
  __syncthreads();

  const int NFh = L0 ? 2 : 1;
  float hreg[2][4], ureg[2][4], rhv[2][4];
#pragma unroll
  for (int f = 0; f < 2; ++f)
#pragma unroll
    for (int e = 0; e < 4; ++e) {
      int row = row0 + mw + kg * 4 + e;
      hreg[f][e] = (f < NFh)
          ? P.hs0init[(size_t)row * 512 + n0 + f * 16 + l15] : 0.f;
      ureg[f][e] = 0.f; rhv[f][e] = 0.f;
    }

  if (L0) {
    for (int s = 0; s < 40; ++s) {
      slot_wait<8>(sync, XGR(s), 12u);          // xg0 slice ready (fast)
      const float* xg = P.xg0 + (size_t)s * 128 * 1536;
      float xvu[2][4], xvr[2][4];
#pragma unroll
      for (int f = 0; f < 2; ++f)
#pragma unroll
        for (int e = 0; e < 4; ++e) {
          int row = row0 + mw + kg * 4 + e;
          int col = n0 + f * 16 + l15;
          xvu[f][e] = xg[(size_t)row * 1536 + col];
          xvr[f][e] = xg[(size_t)row * 1536 + 512 + col];
        }
      if (s >= 1) slot_wait<8>(sync, CHB0(half, s), 16u);
      f32x4 acc4[4];
      const bf16_t* A0 = P.hb0_seq + (size_t)s * SLOT + (size_t)row0 * 512;
      tile_gemm64<512, 4>(A0, A0, BsRU, wave, lane, acc4);
#pragma unroll
      for (int f = 0; f < 2; ++f)
#pragma unroll
        for (int e = 0; e < 4; ++e) {
          float pu = acc4[f][e]     + xvu[f][e];
          float pr = acc4[f + 2][e] + xvr[f][e];
          ureg[f][e] = 1.f / (1.f + expf(-pu));
          rhv[f][e]  = (1.f / (1.f + expf(-pr))) * hreg[f][e];
        }
      publish64<32>(P.rh0s + (size_t)s * SLOT, row0, n0, rhv, tb, wave, lane, tid);
      slot_inc(sync, CRH0(half, s));
      float xvc[2][4];
#pragma unroll
      for (int f = 0; f < 2; ++f)
#pragma unroll
        for (int e = 0; e < 4; ++e) {
          int row = row0 + mw + kg * 4 + e;
          int col = n0 + f * 16 + l15;
          xvc[f][e] = xg[(size_t)row * 1536 + 1024 + col];
        }
      slot_wait<8>(sync, CRH0(half, s), 16u);

      f32x4 acc2[2];
      const bf16_t* Arh = P.rh0s + (size_t)s * SLOT + (size_t)row0 * 512;
      tile_gemm64<512, 2>(Arh, Arh, BsC, wave, lane, acc2);
#pragma unroll
      for (int f = 0; f < 2; ++f)
#pragma unroll
        for (int e = 0; e < 4; ++e) {
          float c = tanhf(acc2[f][e] + xvc[f][e]);
          float u = ureg[f][e];
          hreg[f][e] = u * hreg[f][e] + (1.f - u) * c;
          rhv[f][e] = hreg[f][e];
        }
      publish64<32>(P.hb0_seq + (size_t)(s + 1) * SLOT, row0, n0, rhv, tb, wave, lane, tid);
      slot_inc(sync, CHB0(half, s + 1));
    }
  } else {
    const float bvu = P.bu[512 + n0 + l15];
    const float bvr = P.br[512 + n0 + l15];
    const float bvc = P.bc[512 + n0 + l15];
    for (int s = 1; s <= 40; ++s) {
      // Wait only the (ahead-running) L0 product; precompute hb0-halves of
      // BOTH L1 GEMMs before touching the critical hb1/rh1 operands.
      slot_wait<8>(sync, CHB0(half, s), 16u);
      const bf16_t* Ah0 = P.hb0_seq + (size_t)s * SLOT + (size_t)row0 * 512;
      f32x4 accRU[2], accC[1];
      tile_gemm64_h<2, false>(Ah0, BsRU, 0, wave, lane, accRU);
      tile_gemm64_h<1, false>(Ah0, BsC,  0, wave, lane, accC);
      // ---- critical: hb1[s-1] half of RU1 ----
      if (s >= 2) slot_wait<8>(sync, CHB1(half, s - 1), 32u);
      tile_gemm64_h<2, true>(P.hb1_seq + (size_t)(s - 1) * SLOT + (size_t)row0 * 512,
                             BsRU, 512, wave, lane, accRU);
#pragma unroll
      for (int e = 0; e < 4; ++e) {
        float pu = accRU[0][e] + bvu;
        float pr = accRU[1][e] + bvr;
        ureg[0][e] = 1.f / (1.f + expf(-pu));
        rhv[0][e]  = (1.f / (1.f + expf(-pr))) * hreg[0][e];
      }
      publish64<16>(P.rh1s + (size_t)s * SLOT, row0, n0, rhv, tb, wave, lane, tid);
      slot_inc(sync, CRH1(half, s));
      slot_wait<8>(sync, CRH1(half, s), 32u);
      // ---- critical: rh1[s] half of C1 ----
      tile_gemm64_h<1, true>(P.rh1s + (size_t)s * SLOT + (size_t)row0 * 512,
                             BsC, 512, wave, lane, accC);
#pragma unroll
      for (int e = 0; e < 4; ++e) {
        float c = tanhf(accC[0][e] + bvc);
        float u = ureg[0][e];
        hreg[0][e] = u * hreg[0][e] + (1.f - u) * c;
        rhv[0][e] = hreg[0][e];
      }
      publish64<16>(P.hb1_seq + (size_t)s * SLOT, row0, n0, rhv, tb, wave, lane, tid);
      slot_inc(sync, CHB1(half, s));
    }
  }

  float* dst = P.out_hfin + (L0 ? 0 : 65536);
#pragma unroll
  for (int f = 0; f < 2; ++f)
    if (f < NFh)
#pragma unroll
      for (int e = 0; e < 4; ++e) {
        int row = row0 + mw + kg * 4 + e;
        dst[(size_t)row * 512 + n0 + f * 16 + l15] = hreg[f][e];
      }
}

// ============================================================================
// h0 = tanh(vgg @ W_in + b_in) via bf16 MFMA, split-K=8.
// ============================================================================
__global__ __launch_bounds__(256) void h0_gemm(
    const bf16_t* __restrict__ vggb, const bf16_t* __restrict__ Wint,
    float* __restrict__ part)
{
  const int bn = blockIdx.x * 128, z = blockIdx.y, k0 = z * 512;
  const int tid = threadIdx.x;
  const int wave = tid >> 6, lane = tid & 63;
  const int wm = (wave >> 1) * 64, wn = (wave & 1) * 64;
  const int l15 = lane & 15, kg = lane >> 4;
  const bf16_t* Ap = vggb + (size_t)(wm + l15) * 4096 + k0 + kg * 8;
  const bf16_t* Bp = Wint + (size_t)(bn + wn + l15) * 4096 + k0 + kg * 8;
  f32x4 acc[4][4];
#pragma unroll
  for (int i = 0; i < 4; ++i)
#pragma unroll
    for (int j = 0; j < 4; ++j)
#pragma unroll
      for (int e = 0; e < 4; ++e) acc[i][j][e] = 0.f;
  for (int kk = 0; kk < 512; kk += 32) {
    bf16x8 a[4], b[4];
#pragma unroll
    for (int i = 0; i < 4; ++i) a[i] = *(const bf16x8*)(Ap + (size_t)i * 16 * 4096 + kk);
#pragma unroll
    for (int j = 0; j < 4; ++j) b[j] = *(const bf16x8*)(Bp + (size_t)j * 16 * 4096 + kk);
#pragma unroll
    for (int i = 0; i < 4; ++i)
#pragma unroll
      for (int j = 0; j < 4; ++j)
        acc[i][j] = __builtin_amdgcn_mfma_f32_16x16x32_bf16(a[i], b[j], acc[i][j], 0, 0, 0);
  }
#pragma unroll
  for (int fm = 0; fm < 4; ++fm)
#pragma unroll
    for (int fn = 0; fn < 4; ++fn) {
      int n = bn + wn + fn * 16 + l15;
#pragma unroll
      for (int e = 0; e < 4; ++e) {
        int m = wm + fm * 16 + kg * 4 + e;
        part[(size_t)z * SLOT + m * 512 + n] = acc[fm][fn][e];
      }
    }
}

__global__ void h0_fin(const float* __restrict__ part, const float* __restrict__ bin,
                       float* __restrict__ hs0init,
                       bf16_t* __restrict__ hb00, bf16_t* __restrict__ hb10)
{
  int i = blockIdx.x * 256 + threadIdx.x;   // 65536
  int n = i & 511;
  float s = bin[n];
#pragma unroll
  for (int z = 0; z < 8; ++z) s += part[(size_t)z * SLOT + i];
  float v = tanhf(s);
  hs0init[i] = v;
  hb00[i] = (bf16_t)v; hb10[i] = (bf16_t)v;
}

struct TJob { const float* src; bf16_t* dst; int K; int dstld; };
struct TJobs4 { TJob j[4]; };
__global__ void transpose_gen(TJobs4 jobs)
{
  TJob jb = jobs.j[blockIdx.z];
  int k0 = blockIdx.x * 32;
  if (k0 >= jb.K) return;
  int n0 = blockIdx.y * 32;
  __shared__ float tile[32][33];
  int tx = threadIdx.x, ty = threadIdx.y;
#pragma unroll
  for (int r = 0; r < 4; ++r)
    tile[ty + 8 * r][tx] = jb.src[(size_t)(k0 + ty + 8 * r) * 512 + n0 + tx];
  __syncthreads();
#pragma unroll
  for (int r = 0; r < 4; ++r)
    jb.dst[(size_t)(n0 + ty + 8 * r) * jb.dstld + k0 + tx] = (bf16_t)tile[tx][ty + 8 * r];
}

struct TJobs6 { TJob j[6]; };
__global__ void transpose_gen6(TJobs6 jobs)
{
  TJob jb = jobs.j[blockIdx.z];
  int k0 = blockIdx.x * 32;
  if (k0 >= jb.K) return;
  int n0 = blockIdx.y * 32;
  __shared__ float tile[32][33];
  int tx = threadIdx.x, ty = threadIdx.y;
#pragma unroll
  for (int r = 0; r < 4; ++r)
    tile[ty + 8 * r][tx] = jb.src[(size_t)(k0 + ty + 8 * r) * 512 + n0 + tx];
  __syncthreads();
#pragma unroll
  for (int r = 0; r < 4; ++r)
    jb.dst[(size_t)(n0 + ty + 8 * r) * jb.dstld + k0 + tx] = (bf16_t)tile[tx][ty + 8 * r];
}

__global__ void transpose_wout(const float* __restrict__ W, bf16_t* __restrict__ dst)
{
  __shared__ float tile[32][33];
  int k0 = blockIdx.x * 32, n0 = blockIdx.y * 32;
  int tx = threadIdx.x, ty = threadIdx.y;
#pragma unroll
  for (int r = 0; r < 4; ++r) {
    int n = n0 + tx;
    tile[ty + 8 * r][tx] = (n < VV) ? W[(size_t)(k0 + ty + 8 * r) * VV + n] : 0.f;
  }
  __syncthreads();
#pragma unroll
  for (int r = 0; r < 4; ++r)
    dst[(size_t)(n0 + ty + 8 * r) * 512 + k0 + tx] = (bf16_t)tile[tx][ty + 8 * r];
}

// ============================================================================
extern "C" void kernel_launch(void* const* d_in, const int* in_sizes, int n_in,
                              void* d_out, int out_size, void* d_ws, size_t ws_size,
                              hipStream_t stream)
{
  const int*   tok = (const int*)  d_in[0];
  const float* vgg = (const float*)d_in[1];
  const float* emb = (const float*)d_in[2];
  const float* Win = (const float*)d_in[3];
  const float* bin = (const float*)d_in[4];
  const float* Wu  = (const float*)d_in[5];
  const float* bu  = (const float*)d_in[6];
  const float* Wr  = (const float*)d_in[7];
  const float* br  = (const float*)d_in[8];
  const float* Wc  = (const float*)d_in[9];
  const float* bc  = (const float*)d_in[10];
  const float* Wo  = (const float*)d_in[11];
  const float* bo  = (const float*)d_in[12];
  float* out = (float*)d_out;

  size_t off = 0;
  auto alloc = [&](size_t bytes) -> void* {
    void* p = (char*)d_ws + off;
    off += (bytes + 255) & ~(size_t)255;
    return p;
  };
  float*  hs0init = (float*) alloc(SLOT * 4);
  bf16_t* rh0s  = (bf16_t*)alloc(41 * SLOT * 2);
  bf16_t* rh1s  = (bf16_t*)alloc(41 * SLOT * 2);
  bf16_t* hb0_seq = (bf16_t*)alloc(41 * SLOT * 2);
  bf16_t* hb1_seq = (bf16_t*)alloc(41 * SLOT * 2);
  bf16_t* Aemb  = (bf16_t*)alloc((size_t)TT * BB * 512 * 2);
  float*  xg0   = (float*) alloc((size_t)TT * BB * 1536 * 4);
  bf16_t* Btx0  = (bf16_t*)alloc((size_t)1536 * 512 * 2);
  bf16_t* Btru0 = (bf16_t*)alloc((size_t)1024 * 512 * 2);
  bf16_t* Btc0  = (bf16_t*)alloc((size_t)512 * 512 * 2);
  bf16_t* Bt1ru = (bf16_t*)alloc((size_t)1024 * 1024 * 2);
  bf16_t* Btc1  = (bf16_t*)alloc((size_t)512 * 1024 * 2);
  bf16_t* Wto   = (bf16_t*)alloc((size_t)10112 * 512 * 2);
  bf16_t* Wint  = (bf16_t*)alloc((size_t)512 * 4096 * 2);
  bf16_t* vggb  = (bf16_t*)alloc((size_t)128 * 4096 * 2);
  float*  h0part= (float*) alloc(8 * SLOT * 4);
  float*  xbias = (float*) alloc(2 * 1536 * 4);
  unsigned* syncws = (unsigned*) alloc(NSYNCW * 4);
  if (off > ws_size) return;

  // ---- merged misc prep (zero_sync | xbias | vgg->bf16 | emb gather) ----
  MiscArgs ma;
  ma.sync = syncws; ma.bu = bu; ma.br = br; ma.bc = bc; ma.xbias = xbias;
  ma.vgg = vgg; ma.vggb = vggb; ma.tok = tok; ma.emb = emb; ma.Aemb = Aemb;
  prep_misc<<<3085, 256, 0, stream>>>(ma);

  // ---- weight transposes ----
  TJobs4 t4;
  t4.j[0] = { Wu,          Btx0,           512, 512 };
  t4.j[1] = { Wr,          Btx0 + 262144,  512, 512 };
  t4.j[2] = { Wc,          Btx0 + 524288,  512, 512 };
  t4.j[3] = { Win,         Wint,           4096, 4096 };
  transpose_gen<<<dim3(128, 16, 4), dim3(32, 8), 0, stream>>>(t4);
  TJobs6 t6;
  t6.j[0] = { Wu + 262144, Btru0,            512, 512 };
  t6.j[1] = { Wr + 262144, Btru0 + 262144,   512, 512 };
  t6.j[2] = { Wc + 262144, Btc0,             512, 512 };
  t6.j[3] = { Wu + 524288, Bt1ru,            1024, 1024 };
  t6.j[4] = { Wr + 524288, Bt1ru + 524288,   1024, 1024 };
  t6.j[5] = { Wc + 524288, Btc1,             1024, 1024 };
  transpose_gen6<<<dim3(32, 16, 6), dim3(32, 8), 0, stream>>>(t6);
  transpose_wout<<<dim3(16, 316), dim3(32, 8), 0, stream>>>(Wo, Wto);

  // ---- h0 init ----
  h0_gemm<<<dim3(4, 8), 256, 0, stream>>>(vggb, Wint, h0part);
  h0_fin<<<256, 256, 0, stream>>>(h0part, bin, hs0init, hb0_seq, hb1_seq);

  // ---- persistent fused kernel (xg0 + recurrence + logits) ----
  PArgs pa;
  pa.Btru0 = Btru0; pa.Bt1ru = Bt1ru; pa.Btc0 = Btc0; pa.Btc1 = Btc1;
  pa.bu = bu; pa.br = br; pa.bc = bc; pa.hs0init = hs0init;
  pa.xg0 = xg0; pa.Aemb = Aemb; pa.Btx0 = Btx0; pa.xbias = xbias;
  pa.hb0_seq = hb0_seq; pa.hb1_seq = hb1_seq;
  pa.rh0s = rh0s; pa.rh1s = rh1s;
  pa.Wto = Wto; pa.bo = bo; pa.out = out;
  pa.out_hfin = out + (size_t)BB * TT * VV;
  pa.sync = syncws;
  gru_persist<<<NGRID, 256, 0, stream>>>(pa);
}